// Round 1
// baseline (1288.135 us; speedup 1.0000x reference)
//
#include <hip/hip_runtime.h>
#include <hip/hip_fp16.h>
#include <math.h>

#define NLOR  65536
#define NG    128
#define PLANE (NG * NG)
#define NSUB  2
#define KG    8               /* planes per proj block */
#define NKG   (NG / KG)       /* 16 plane groups */

#define VOX    1.671875f                 /* 214/128 exact */
#define XMIN  (-107.0f)
/* weight arg in cell units: (pi/2)(m+d)^2 */
#define C2     1.57079632679f

// Per-LOR precomputed affine params, 8 floats:
//   [0]=u0 [1]=du [2]=v0 [3]=dv   (y-family stored pre-swapped)
//   [4]=t0 [5]=dt [6]=cf (filled by reduce_cf3) [7]=pad
#define PRM_STRIDE 8

// ---------------------------------------------------------------------------
// Tiled 3D permute body (f32 out). Output ((P*128 + Q)*128 + R); input addr
// P*SP + Q*SQ + R*SR (+ s*volume for NSUM sub-buffers). CONTIG: which of
// {P(0),Q(1)} is the tiled (input-contiguous) axis; the other is b.
// ---------------------------------------------------------------------------
template<int SP, int SQ, int SR, int CONTIG, int NSUM, bool ACCUM, bool FINAL>
__device__ __forceinline__ void permute_body(
    const float* __restrict__ in, float* __restrict__ out,
    const float* __restrict__ img, const float* __restrict__ eff,
    int b, float (*tile)[33])
{
    const int c0 = blockIdx.x * 32;
    const int r0 = blockIdx.y * 32;
    const int tx = threadIdx.x, ty = threadIdx.y;

#pragma unroll
    for (int m = 0; m < 4; ++m) {
        const int C = c0 + tx;
        const int R = r0 + ty + 8 * m;
        const int P = (CONTIG == 0) ? C : b;
        const int Q = (CONTIG == 0) ? b : C;
        const int a = P * SP + Q * SQ + R * SR;
        float v = 0.0f;
#pragma unroll
        for (int s = 0; s < NSUM; ++s) v += in[a + s * NG * PLANE];
        tile[ty + 8 * m][tx] = v;
    }
    __syncthreads();
#pragma unroll
    for (int m = 0; m < 4; ++m) {
        const int R = r0 + tx;
        const int C = c0 + ty + 8 * m;
        const int P = (CONTIG == 0) ? C : b;
        const int Q = (CONTIG == 0) ? b : C;
        const int o = P * PLANE + Q * NG + R;
        float v = tile[tx][ty + 8 * m];
        if (ACCUM) v += out[o];
        if (FINAL) v = img[o] / (eff[o] + 1e-8f) * v;
        out[o] = v;
    }
}

// Same body but writing __half (for the staged image volumes).
template<int SP, int SQ, int SR, int CONTIG>
__device__ __forceinline__ void permute_half_body(
    const float* __restrict__ in, __half* __restrict__ out,
    int b, float (*tile)[33])
{
    const int c0 = blockIdx.x * 32;
    const int r0 = blockIdx.y * 32;
    const int tx = threadIdx.x, ty = threadIdx.y;

#pragma unroll
    for (int m = 0; m < 4; ++m) {
        const int C = c0 + tx;
        const int R = r0 + ty + 8 * m;
        const int P = (CONTIG == 0) ? C : b;
        const int Q = (CONTIG == 0) ? b : C;
        tile[ty + 8 * m][tx] = in[P * SP + Q * SQ + R * SR];
    }
    __syncthreads();
#pragma unroll
    for (int m = 0; m < 4; ++m) {
        const int R = r0 + tx;
        const int C = c0 + ty + 8 * m;
        const int P = (CONTIG == 0) ? C : b;
        const int Q = (CONTIG == 0) ? b : C;
        const int o = P * PLANE + Q * NG + R;
        out[o] = __float2half(tile[tx][ty + 8 * m]);
    }
}

// Both image permutes in one launch: b<128 -> imgPz [z][x][y]; else imgPx [y][z][x].
__global__ __launch_bounds__(256)
void perm_img2(const float* __restrict__ image,
               __half* __restrict__ imgPz, __half* __restrict__ imgPx)
{
    __shared__ float tile[32][33];
    const int b = blockIdx.z;
    if (b < 128)
        permute_half_body<1, 16384, 128, 0>(image, imgPz, b, tile);
    else
        permute_half_body<128, 1, 16384, 1>(image, imgPx, b - 128, tile);
}

__global__ __launch_bounds__(256)
void perm_outA(const float* __restrict__ in, float* __restrict__ out)
{
    __shared__ float tile[32][33];
    permute_body<128, 1, 16384, 1, NSUB, false, false>(in, out, nullptr, nullptr, blockIdx.z, tile);
}

__global__ __launch_bounds__(256)
void perm_outB(const float* __restrict__ in, float* __restrict__ out,
               const float* __restrict__ img, const float* __restrict__ eff)
{
    __shared__ float tile[32][33];
    permute_body<1, 16384, 128, 0, NSUB, true, true>(in, out, img, eff, blockIdx.z, tile);
}

// ---------------------------------------------------------------------------
// Per-LOR affine geometry precompute (runs once, before projection).
// t(k) = t0 + k*dt ; u(k) = u0 + k*du ; v(k) = v0 + k*dv, k = plane index.
// y-family (f==1) stores u/v pre-swapped so downstream kernels are uniform.
// ---------------------------------------------------------------------------
__global__ __launch_bounds__(256)
void lor_prep(const float* __restrict__ zl, const float* __restrict__ yl,
              const float* __restrict__ xl,
              float* __restrict__ prmz, float* __restrict__ prmy,
              float* __restrict__ prmx)
{
    const int f = blockIdx.y;
    const float* lors = (f == 0) ? zl : (f == 1) ? yl : xl;
    float* prm        = (f == 0) ? prmz : (f == 1) ? prmy : prmx;
    const int lor = blockIdx.x * 256 + threadIdx.x;

    const float p1x = lors[0 * NLOR + lor];
    const float p1y = lors[1 * NLOR + lor];
    const float p1z = lors[2 * NLOR + lor];
    const float dx  = lors[3 * NLOR + lor] - p1x;
    const float dy  = lors[4 * NLOR + lor] - p1y;
    float dz = lors[5 * NLOR + lor] - p1z;
    dz = (fabsf(dz) < 1e-6f) ? 1e-6f : dz;
    const float rdz = 1.0f / dz;

    const float t0 = (XMIN + 0.5f * VOX - p1z) * rdz;   /* t at plane k=0 */
    const float dt = VOX * rdz;
    float u0 = (fmaf(t0, dx, p1x) - XMIN) * (1.0f / VOX) - 0.5f;
    float v0 = (fmaf(t0, dy, p1y) - XMIN) * (1.0f / VOX) - 0.5f;
    float du = dx * rdz;
    float dv = dy * rdz;
    if (f == 1) {   /* y-family consumes the z-permuted volume with axes swapped */
        float tmp = u0; u0 = v0; v0 = tmp;
        tmp = du; du = dv; dv = tmp;
    }
    float4* p4 = (float4*)(prm + (size_t)lor * PRM_STRIDE);
    p4[0] = make_float4(u0, du, v0, dv);
    p4[1] = make_float4(t0, dt, 0.0f, 0.0f);
}

// ---------------------------------------------------------------------------
// Projection. Plane staged in LDS as half2 pairs (32 KB). blockIdx.x = plane
// group (XCD = linear_id % 8 = g % 8 -> all chunks of one group share an XCD
// L2, so each XCD fetches only its own groups' planes). blockIdx.y = chunk.
// ---------------------------------------------------------------------------
template<int NS>
__device__ __forceinline__ void proj_body(
    const float* const* prmv, const unsigned int* __restrict__ imgP,
    float* const* p8v, unsigned int* pl)
{
    const int g     = blockIdx.x;          // 16 plane groups (XCD selector)
    const int chunk = blockIdx.y;          // 32 chunks x 2048 LORs
    const int tid   = threadIdx.x;
    const int lor0  = chunk * 2048 + tid;
    const float k0  = (float)(g * KG);

    float tA[2 * NS], uA[2 * NS], vA[2 * NS], dtA[2 * NS], duA[2 * NS], dvA[2 * NS], sA[2 * NS];
#pragma unroll
    for (int s = 0; s < 2 * NS; ++s) {
        const float* prm = prmv[s >> 1];
        const int lor = lor0 + (s & 1) * 1024;
        const float4* p4 = (const float4*)(prm + (size_t)lor * PRM_STRIDE);
        const float4 a = p4[0];
        const float4 b = p4[1];
        tA[s] = fmaf(k0, b.y, b.x);  dtA[s] = b.y;
        uA[s] = fmaf(k0, a.y, a.x);  duA[s] = a.y;
        vA[s] = fmaf(k0, a.w, a.z);  dvA[s] = a.w;
        sA[s] = 0.0f;
    }

    for (int st = 0; st < KG; ++st) {
        const int k = g * KG + st;
        const uint4* src = (const uint4*)(imgP + k * (NG * 64));
        uint4* dst = (uint4*)pl;
        for (int i = tid; i < (NG * 64) / 4; i += 1024) dst[i] = src[i];
        __syncthreads();

        const float fst = (float)st;
#pragma unroll
        for (int s = 0; s < 2 * NS; ++s) {
            const float t = fmaf(fst, dtA[s], tA[s]);
            const float u = fmaf(fst, duA[s], uA[s]);
            const float v = fmaf(fst, dvA[s], vA[s]);
            const int i0 = (int)rintf(u);
            const int j0 = (int)rintf(v);
            const float mi = (float)i0 - u;
            const float mj = (float)j0 - v;
            const float mim = mi - 1.0f, mip = mi + 1.0f;
            const float mjm = mj - 1.0f, mjp = mj + 1.0f;
            const float exm = __expf(-C2 * mim * mim);
            const float ex0 = __expf(-C2 * mi  * mi );
            const float exq = __expf(-C2 * mip * mip);
            const float eym = __expf(-C2 * mjm * mjm);
            const float ey0 = __expf(-C2 * mj  * mj );
            const float eyq = __expf(-C2 * mjp * mjp);

            const int odd = j0 & 1;
            const float lA = odd ? eym : 0.0f;
            const float hA = odd ? ey0 : eym;
            const float lB = odd ? eyq : ey0;
            const float hB = odd ? 0.0f : eyq;
            const int p0 = min(max((j0 - 1) >> 1, 0), 62);
            const int ib = min(max(i0 - 1, 0), 125);

            const float exv[3] = {exm, ex0, exq};
            float acc = 0.0f;
#pragma unroll
            for (int a = 0; a < 3; ++a) {
                const int rowb = (ib + a) << 6;
                const unsigned int Aw = pl[rowb + p0];
                const unsigned int Bw = pl[rowb + p0 + 1];
                const float2 A = __half22float2(*reinterpret_cast<const __half2*>(&Aw));
                const float2 B = __half22float2(*reinterpret_cast<const __half2*>(&Bw));
                acc += exv[a] * (lA * A.x + hA * A.y + lB * B.x + hB * B.y);
            }
            const bool tin = (t >= 0.0f) && (t <= 1.0f);
            sA[s] += tin ? acc : 0.0f;
        }
        __syncthreads();
    }
#pragma unroll
    for (int s = 0; s < NS; ++s) {
        p8v[s][g * NLOR + lor0]        = sA[2 * s];
        p8v[s][g * NLOR + lor0 + 1024] = sA[2 * s + 1];
    }
}

// blockIdx.z==0: z+y streams on imgPz; ==1: x stream on imgPx.
__global__ __launch_bounds__(1024, 8)
void proj_all(const float* __restrict__ prmz, const float* __restrict__ prmy,
              const float* __restrict__ prmx,
              const unsigned int* __restrict__ imgPz, const unsigned int* __restrict__ imgPx,
              float* __restrict__ p8z, float* __restrict__ p8y,
              float* __restrict__ p8x)
{
    __shared__ unsigned int pl[NG * 64];     /* 32 KB: plane as half2 pairs */
    if (blockIdx.z == 0) {
        const float* prmv[2] = {prmz, prmy};
        float* p8v[2] = {p8z, p8y};
        proj_body<2>(prmv, imgPz, p8v, pl);
    } else {
        const float* prmv[1] = {prmx};
        float* p8v[1] = {p8x};
        proj_body<1>(prmv, imgPx, p8v, pl);
    }
}

// ---------------------------------------------------------------------------
// cf for all three passes in one dispatch (blockIdx.y selects the pass).
// Writes cf into slot 6 of the per-LOR param struct (same 32B line bp reads).
// ---------------------------------------------------------------------------
__global__ __launch_bounds__(256)
void reduce_cf3(const float* __restrict__ zl, const float* __restrict__ yl,
                const float* __restrict__ xl,
                const float* __restrict__ p8z, const float* __restrict__ p8y,
                const float* __restrict__ p8x,
                float* __restrict__ prmz, float* __restrict__ prmy,
                float* __restrict__ prmx)
{
    const int which = blockIdx.y;
    const float* lors  = (which == 0) ? zl  : (which == 1) ? yl  : xl;
    const float* part8 = (which == 0) ? p8z : (which == 1) ? p8y : p8x;
    float*       prm   = (which == 0) ? prmz : (which == 1) ? prmy : prmx;

    const int lor = blockIdx.x * 256 + threadIdx.x;
    float s = 0.0f;
#pragma unroll
    for (int g = 0; g < NKG; ++g) s += part8[g * NLOR + lor];

    const float p1x = lors[0 * NLOR + lor];
    const float p1y = lors[1 * NLOR + lor];
    const float p1z = lors[2 * NLOR + lor];
    const float dx  = lors[3 * NLOR + lor] - p1x;
    const float dy  = lors[4 * NLOR + lor] - p1y;
    const float dz0 = lors[5 * NLOR + lor] - p1z;
    const float L = sqrtf(dx * dx + dy * dy + dz0 * dz0);
    const float adz = fmaxf(fabsf(dz0), 1e-6f);
    const float dl = VOX * L / adz;
    prm[(size_t)lor * PRM_STRIDE + 6] = dl / (s * dl + 1e-8f);
}

// ---------------------------------------------------------------------------
// bp deposit: affine params + 9 native f32 LDS atomics (ds_add_f32).
// f32 addresses spread over all 32 banks (u64 packing only hit even pairs).
// ---------------------------------------------------------------------------
__device__ __forceinline__ void bp_deposit(const float* __restrict__ prm,
    int lor, float fk, float* __restrict__ pl)
{
    const float4* p4 = (const float4*)(prm + (size_t)lor * PRM_STRIDE);
    const float4 a = p4[0];
    const float4 b = p4[1];
    const float t = fmaf(fk, b.y, b.x);
    const float u = fmaf(fk, a.y, a.x);
    const float v = fmaf(fk, a.w, a.z);
    const float fi = rintf(u);
    const float fj = rintf(v);
    const int i0 = (int)fi;
    const int j0 = (int)fj;
    const bool tin = (t >= 0.0f) && (t <= 1.0f);
    const float cfs = tin ? b.z : 0.0f;

    const float mi = fi - u;
    const float mj = fj - v;
    const float mim = mi - 1.0f, mip = mi + 1.0f;
    const float mjm = mj - 1.0f, mjp = mj + 1.0f;
    const float exm = __expf(-C2 * mim * mim) * cfs;
    const float ex0 = __expf(-C2 * mi  * mi ) * cfs;
    const float exq = __expf(-C2 * mip * mip) * cfs;
    const float eym = __expf(-C2 * mjm * mjm);
    const float ey0 = __expf(-C2 * mj  * mj );
    const float eyq = __expf(-C2 * mjp * mjp);

    const int ib = min(max(i0 - 1, 0), NG - 3);
    const int jb = min(max(j0 - 1, 0), NG - 3);
    float* base = pl + ib * NG + jb;

    const float exv[3] = {exm, ex0, exq};
#pragma unroll
    for (int aa = 0; aa < 3; ++aa) {
        float* row = base + aa * NG;           /* +0,+4,+8 / +512... fold to ds imm offsets */
        atomicAdd(row + 0, exv[aa] * eym);
        atomicAdd(row + 1, exv[aa] * ey0);
        atomicAdd(row + 2, exv[aa] * eyq);
    }
}

// ---------------------------------------------------------------------------
// All backprojection in one launch. blockIdx.y==0: z+y -> bpsubA (z-family);
// ==1: x -> bpsubB (y-family). NSUB=2 sub-volumes.
// ---------------------------------------------------------------------------
__global__ __launch_bounds__(1024)
void bp_all(const float* __restrict__ prmz, const float* __restrict__ prmy,
            const float* __restrict__ prmx,
            float* __restrict__ bpsubA, float* __restrict__ bpsubB)
{
    __shared__ float pl[NG * NG];              /* 64 KB f32 plane accumulator */
    const int k   = blockIdx.x >> 1;
    const int sub = blockIdx.x & 1;
    const int tid = threadIdx.x;

    for (int i = tid; i < NG * NG; i += 1024) pl[i] = 0.0f;
    __syncthreads();

    const float fk = (float)k;
    const int lo = sub * (NLOR / NSUB), hi = lo + NLOR / NSUB;
    float* bpsub;
    if (blockIdx.y == 0) {
        for (int lor = lo + tid; lor < hi; lor += 1024)
            bp_deposit(prmz, lor, fk, pl);
        for (int lor = lo + tid; lor < hi; lor += 1024)
            bp_deposit(prmy, lor, fk, pl);
        bpsub = bpsubA;
    } else {
        for (int lor = lo + tid; lor < hi; lor += 1024)
            bp_deposit(prmx, lor, fk, pl);
        bpsub = bpsubB;
    }
    __syncthreads();

    float4* out4 = (float4*)(bpsub + ((size_t)sub * NG + k) * PLANE);
    const float4* pl4 = (const float4*)pl;
    for (int i = tid; i < (NG * NG) / 4; i += 1024) out4[i] = pl4[i];
}

extern "C" void kernel_launch(void* const* d_in, const int* in_sizes, int n_in,
                              void* d_out, int out_size, void* d_ws, size_t ws_size,
                              hipStream_t stream) {
    const float* image = (const float*)d_in[0];
    const float* eff   = (const float*)d_in[1];
    const float* xl    = (const float*)d_in[2];
    const float* yl    = (const float*)d_in[3];
    const float* zl    = (const float*)d_in[4];
    float* out = (float*)d_out;

    char* ws = (char*)d_ws;
    __half* imgPz = (__half*)(ws);                       //  4 MB [z][x][y] half
    __half* imgPx = (__half*)(ws + (size_t)( 4 << 20));  //  4 MB [y][z][x] half
    float* bpsubA = (float*)(ws + (size_t)( 8 << 20));   // 16 MB [sub][z][x][y]
    float* bpsubB = (float*)(ws + (size_t)(24 << 20));   // 16 MB [sub][y][z][x]
    float* p8z    = (float*)(ws + (size_t)(40 << 20));   //  4 MB
    float* p8y    = (float*)(ws + (size_t)(44 << 20));   //  4 MB
    float* p8x    = (float*)(ws + (size_t)(48 << 20));   //  4 MB
    float* prmz   = (float*)(ws + (size_t)(52 << 20));   //  2 MB per-LOR params
    float* prmy   = (float*)(ws + (size_t)(54 << 20));   //  2 MB
    float* prmx   = (float*)(ws + (size_t)(56 << 20));   //  2 MB

    const dim3 tb(32, 8);

    // 0) per-LOR affine geometry params (all 3 families)
    lor_prep<<<dim3(NLOR / 256, 3), 256, 0, stream>>>(zl, yl, xl, prmz, prmy, prmx);
    // 1) both image permutes (f32 -> half volumes)
    perm_img2<<<dim3(4, 4, 256), tb, 0, stream>>>(image, imgPz, imgPx);
    // 2) all projections; grid.x = plane group for XCD L2 locality
    proj_all<<<dim3(16, 32, 2), 1024, 0, stream>>>(prmz, prmy, prmx,
        (const unsigned int*)imgPz, (const unsigned int*)imgPx, p8z, p8y, p8x);
    // 3) correction factors -> params slot 6
    reduce_cf3<<<dim3(256, 3), 256, 0, stream>>>(zl, yl, xl, p8z, p8y, p8x, prmz, prmy, prmx);
    // 4) all backprojection (z+y -> bpsubA | x -> bpsubB)
    bp_all<<<dim3(128 * NSUB, 2), 1024, 0, stream>>>(prmz, prmy, prmx, bpsubA, bpsubB);
    // 5) z+y accumulator -> out (overwrite)
    perm_outA<<<dim3(4, 4, 128), tb, 0, stream>>>(bpsubA, out);
    // 6) x accumulator -> out (accumulate + fused finalize)
    perm_outB<<<dim3(4, 4, 128), tb, 0, stream>>>(bpsubB, out, image, eff);
}

// Round 2
// 1280.438 us; speedup vs baseline: 1.0060x; 1.0060x over previous
//
#include <hip/hip_runtime.h>
#include <hip/hip_fp16.h>
#include <math.h>

#define NLOR  65536
#define NG    128
#define PLANE (NG * NG)
#define NSUB  2
#define KG    8               /* planes per proj block */
#define NKG   (NG / KG)       /* 16 plane groups */

#define VOX    1.671875f                 /* 214/128 exact */
#define XMIN  (-107.0f)
/* weight arg in cell units: (pi/2)(m+d)^2 */
#define C2     1.57079632679f

// Per-LOR precomputed affine params, 8 floats:
//   [0]=u0 [1]=du [2]=v0 [3]=dv   (y-family stored pre-swapped)
//   [4]=t0 [5]=dt [6]=cf (filled by reduce_cf3) [7]=pad
#define PRM_STRIDE 8

// Native non-returning fp32 LDS atomic. Plain atomicAdd(float*) on LDS lowers
// to a CAS retry loop under IEEE-denormal mode (round-1 post-mortem: 12x
// regression, VALUBusy 3.9%). ds_add_f32 is the hardware instruction; the
// shared-array pointer is compiler-inferred AS(3) so the cast is a no-op and
// yields the 32-bit LDS byte offset.
__device__ __forceinline__ void lds_fadd(float* p, float v)
{
    auto p3 = (__attribute__((address_space(3))) float*)p;
    asm volatile("ds_add_f32 %0, %1"
                 :: "v"((unsigned)(size_t)p3), "v"(v)
                 : "memory");
}

// ---------------------------------------------------------------------------
// Tiled 3D permute body (f32 out). Output ((P*128 + Q)*128 + R); input addr
// P*SP + Q*SQ + R*SR (+ s*volume for NSUM sub-buffers). CONTIG: which of
// {P(0),Q(1)} is the tiled (input-contiguous) axis; the other is b.
// ---------------------------------------------------------------------------
template<int SP, int SQ, int SR, int CONTIG, int NSUM, bool ACCUM, bool FINAL>
__device__ __forceinline__ void permute_body(
    const float* __restrict__ in, float* __restrict__ out,
    const float* __restrict__ img, const float* __restrict__ eff,
    int b, float (*tile)[33])
{
    const int c0 = blockIdx.x * 32;
    const int r0 = blockIdx.y * 32;
    const int tx = threadIdx.x, ty = threadIdx.y;

#pragma unroll
    for (int m = 0; m < 4; ++m) {
        const int C = c0 + tx;
        const int R = r0 + ty + 8 * m;
        const int P = (CONTIG == 0) ? C : b;
        const int Q = (CONTIG == 0) ? b : C;
        const int a = P * SP + Q * SQ + R * SR;
        float v = 0.0f;
#pragma unroll
        for (int s = 0; s < NSUM; ++s) v += in[a + s * NG * PLANE];
        tile[ty + 8 * m][tx] = v;
    }
    __syncthreads();
#pragma unroll
    for (int m = 0; m < 4; ++m) {
        const int R = r0 + tx;
        const int C = c0 + ty + 8 * m;
        const int P = (CONTIG == 0) ? C : b;
        const int Q = (CONTIG == 0) ? b : C;
        const int o = P * PLANE + Q * NG + R;
        float v = tile[tx][ty + 8 * m];
        if (ACCUM) v += out[o];
        if (FINAL) v = img[o] / (eff[o] + 1e-8f) * v;
        out[o] = v;
    }
}

// Same body but writing __half (for the staged image volumes).
template<int SP, int SQ, int SR, int CONTIG>
__device__ __forceinline__ void permute_half_body(
    const float* __restrict__ in, __half* __restrict__ out,
    int b, float (*tile)[33])
{
    const int c0 = blockIdx.x * 32;
    const int r0 = blockIdx.y * 32;
    const int tx = threadIdx.x, ty = threadIdx.y;

#pragma unroll
    for (int m = 0; m < 4; ++m) {
        const int C = c0 + tx;
        const int R = r0 + ty + 8 * m;
        const int P = (CONTIG == 0) ? C : b;
        const int Q = (CONTIG == 0) ? b : C;
        tile[ty + 8 * m][tx] = in[P * SP + Q * SQ + R * SR];
    }
    __syncthreads();
#pragma unroll
    for (int m = 0; m < 4; ++m) {
        const int R = r0 + tx;
        const int C = c0 + ty + 8 * m;
        const int P = (CONTIG == 0) ? C : b;
        const int Q = (CONTIG == 0) ? b : C;
        const int o = P * PLANE + Q * NG + R;
        out[o] = __float2half(tile[tx][ty + 8 * m]);
    }
}

// Both image permutes in one launch: b<128 -> imgPz [z][x][y]; else imgPx [y][z][x].
__global__ __launch_bounds__(256)
void perm_img2(const float* __restrict__ image,
               __half* __restrict__ imgPz, __half* __restrict__ imgPx)
{
    __shared__ float tile[32][33];
    const int b = blockIdx.z;
    if (b < 128)
        permute_half_body<1, 16384, 128, 0>(image, imgPz, b, tile);
    else
        permute_half_body<128, 1, 16384, 1>(image, imgPx, b - 128, tile);
}

__global__ __launch_bounds__(256)
void perm_outA(const float* __restrict__ in, float* __restrict__ out)
{
    __shared__ float tile[32][33];
    permute_body<128, 1, 16384, 1, NSUB, false, false>(in, out, nullptr, nullptr, blockIdx.z, tile);
}

__global__ __launch_bounds__(256)
void perm_outB(const float* __restrict__ in, float* __restrict__ out,
               const float* __restrict__ img, const float* __restrict__ eff)
{
    __shared__ float tile[32][33];
    permute_body<1, 16384, 128, 0, NSUB, true, true>(in, out, img, eff, blockIdx.z, tile);
}

// ---------------------------------------------------------------------------
// Per-LOR affine geometry precompute (runs once, before projection).
// t(k) = t0 + k*dt ; u(k) = u0 + k*du ; v(k) = v0 + k*dv, k = plane index.
// y-family (f==1) stores u/v pre-swapped so downstream kernels are uniform.
// ---------------------------------------------------------------------------
__global__ __launch_bounds__(256)
void lor_prep(const float* __restrict__ zl, const float* __restrict__ yl,
              const float* __restrict__ xl,
              float* __restrict__ prmz, float* __restrict__ prmy,
              float* __restrict__ prmx)
{
    const int f = blockIdx.y;
    const float* lors = (f == 0) ? zl : (f == 1) ? yl : xl;
    float* prm        = (f == 0) ? prmz : (f == 1) ? prmy : prmx;
    const int lor = blockIdx.x * 256 + threadIdx.x;

    const float p1x = lors[0 * NLOR + lor];
    const float p1y = lors[1 * NLOR + lor];
    const float p1z = lors[2 * NLOR + lor];
    const float dx  = lors[3 * NLOR + lor] - p1x;
    const float dy  = lors[4 * NLOR + lor] - p1y;
    float dz = lors[5 * NLOR + lor] - p1z;
    dz = (fabsf(dz) < 1e-6f) ? 1e-6f : dz;
    const float rdz = 1.0f / dz;

    const float t0 = (XMIN + 0.5f * VOX - p1z) * rdz;   /* t at plane k=0 */
    const float dt = VOX * rdz;
    float u0 = (fmaf(t0, dx, p1x) - XMIN) * (1.0f / VOX) - 0.5f;
    float v0 = (fmaf(t0, dy, p1y) - XMIN) * (1.0f / VOX) - 0.5f;
    float du = dx * rdz;
    float dv = dy * rdz;
    if (f == 1) {   /* y-family consumes the z-permuted volume with axes swapped */
        float tmp = u0; u0 = v0; v0 = tmp;
        tmp = du; du = dv; dv = tmp;
    }
    float4* p4 = (float4*)(prm + (size_t)lor * PRM_STRIDE);
    p4[0] = make_float4(u0, du, v0, dv);
    p4[1] = make_float4(t0, dt, 0.0f, 0.0f);
}

// ---------------------------------------------------------------------------
// Projection. Plane staged in LDS as half2 pairs (32 KB). blockIdx.x = plane
// group (XCD = linear_id % 8 = g % 8 -> all chunks of one group share an XCD
// L2, so each XCD fetches only its own groups' planes). blockIdx.y = chunk.
// ---------------------------------------------------------------------------
template<int NS>
__device__ __forceinline__ void proj_body(
    const float* const* prmv, const unsigned int* __restrict__ imgP,
    float* const* p8v, unsigned int* pl)
{
    const int g     = blockIdx.x;          // 16 plane groups (XCD selector)
    const int chunk = blockIdx.y;          // 32 chunks x 2048 LORs
    const int tid   = threadIdx.x;
    const int lor0  = chunk * 2048 + tid;
    const float k0  = (float)(g * KG);

    float tA[2 * NS], uA[2 * NS], vA[2 * NS], dtA[2 * NS], duA[2 * NS], dvA[2 * NS], sA[2 * NS];
#pragma unroll
    for (int s = 0; s < 2 * NS; ++s) {
        const float* prm = prmv[s >> 1];
        const int lor = lor0 + (s & 1) * 1024;
        const float4* p4 = (const float4*)(prm + (size_t)lor * PRM_STRIDE);
        const float4 a = p4[0];
        const float4 b = p4[1];
        tA[s] = fmaf(k0, b.y, b.x);  dtA[s] = b.y;
        uA[s] = fmaf(k0, a.y, a.x);  duA[s] = a.y;
        vA[s] = fmaf(k0, a.w, a.z);  dvA[s] = a.w;
        sA[s] = 0.0f;
    }

    for (int st = 0; st < KG; ++st) {
        const int k = g * KG + st;
        const uint4* src = (const uint4*)(imgP + k * (NG * 64));
        uint4* dst = (uint4*)pl;
        for (int i = tid; i < (NG * 64) / 4; i += 1024) dst[i] = src[i];
        __syncthreads();

        const float fst = (float)st;
#pragma unroll
        for (int s = 0; s < 2 * NS; ++s) {
            const float t = fmaf(fst, dtA[s], tA[s]);
            const float u = fmaf(fst, duA[s], uA[s]);
            const float v = fmaf(fst, dvA[s], vA[s]);
            const int i0 = (int)rintf(u);
            const int j0 = (int)rintf(v);
            const float mi = (float)i0 - u;
            const float mj = (float)j0 - v;
            const float mim = mi - 1.0f, mip = mi + 1.0f;
            const float mjm = mj - 1.0f, mjp = mj + 1.0f;
            const float exm = __expf(-C2 * mim * mim);
            const float ex0 = __expf(-C2 * mi  * mi );
            const float exq = __expf(-C2 * mip * mip);
            const float eym = __expf(-C2 * mjm * mjm);
            const float ey0 = __expf(-C2 * mj  * mj );
            const float eyq = __expf(-C2 * mjp * mjp);

            const int odd = j0 & 1;
            const float lA = odd ? eym : 0.0f;
            const float hA = odd ? ey0 : eym;
            const float lB = odd ? eyq : ey0;
            const float hB = odd ? 0.0f : eyq;
            const int p0 = min(max((j0 - 1) >> 1, 0), 62);
            const int ib = min(max(i0 - 1, 0), 125);

            const float exv[3] = {exm, ex0, exq};
            float acc = 0.0f;
#pragma unroll
            for (int a = 0; a < 3; ++a) {
                const int rowb = (ib + a) << 6;
                const unsigned int Aw = pl[rowb + p0];
                const unsigned int Bw = pl[rowb + p0 + 1];
                const float2 A = __half22float2(*reinterpret_cast<const __half2*>(&Aw));
                const float2 B = __half22float2(*reinterpret_cast<const __half2*>(&Bw));
                acc += exv[a] * (lA * A.x + hA * A.y + lB * B.x + hB * B.y);
            }
            const bool tin = (t >= 0.0f) && (t <= 1.0f);
            sA[s] += tin ? acc : 0.0f;
        }
        __syncthreads();
    }
#pragma unroll
    for (int s = 0; s < NS; ++s) {
        p8v[s][g * NLOR + lor0]        = sA[2 * s];
        p8v[s][g * NLOR + lor0 + 1024] = sA[2 * s + 1];
    }
}

// blockIdx.z==0: z+y streams on imgPz; ==1: x stream on imgPx.
__global__ __launch_bounds__(1024, 8)
void proj_all(const float* __restrict__ prmz, const float* __restrict__ prmy,
              const float* __restrict__ prmx,
              const unsigned int* __restrict__ imgPz, const unsigned int* __restrict__ imgPx,
              float* __restrict__ p8z, float* __restrict__ p8y,
              float* __restrict__ p8x)
{
    __shared__ unsigned int pl[NG * 64];     /* 32 KB: plane as half2 pairs */
    if (blockIdx.z == 0) {
        const float* prmv[2] = {prmz, prmy};
        float* p8v[2] = {p8z, p8y};
        proj_body<2>(prmv, imgPz, p8v, pl);
    } else {
        const float* prmv[1] = {prmx};
        float* p8v[1] = {p8x};
        proj_body<1>(prmv, imgPx, p8v, pl);
    }
}

// ---------------------------------------------------------------------------
// cf for all three passes in one dispatch (blockIdx.y selects the pass).
// Writes cf into slot 6 of the per-LOR param struct (same 32B line bp reads).
// ---------------------------------------------------------------------------
__global__ __launch_bounds__(256)
void reduce_cf3(const float* __restrict__ zl, const float* __restrict__ yl,
                const float* __restrict__ xl,
                const float* __restrict__ p8z, const float* __restrict__ p8y,
                const float* __restrict__ p8x,
                float* __restrict__ prmz, float* __restrict__ prmy,
                float* __restrict__ prmx)
{
    const int which = blockIdx.y;
    const float* lors  = (which == 0) ? zl  : (which == 1) ? yl  : xl;
    const float* part8 = (which == 0) ? p8z : (which == 1) ? p8y : p8x;
    float*       prm   = (which == 0) ? prmz : (which == 1) ? prmy : prmx;

    const int lor = blockIdx.x * 256 + threadIdx.x;
    float s = 0.0f;
#pragma unroll
    for (int g = 0; g < NKG; ++g) s += part8[g * NLOR + lor];

    const float p1x = lors[0 * NLOR + lor];
    const float p1y = lors[1 * NLOR + lor];
    const float p1z = lors[2 * NLOR + lor];
    const float dx  = lors[3 * NLOR + lor] - p1x;
    const float dy  = lors[4 * NLOR + lor] - p1y;
    const float dz0 = lors[5 * NLOR + lor] - p1z;
    const float L = sqrtf(dx * dx + dy * dy + dz0 * dz0);
    const float adz = fmaxf(fabsf(dz0), 1e-6f);
    const float dl = VOX * L / adz;
    prm[(size_t)lor * PRM_STRIDE + 6] = dl / (s * dl + 1e-8f);
}

// ---------------------------------------------------------------------------
// bp deposit: affine params + 9 native f32 LDS atomics (ds_add_f32 inline
// asm). f32 addresses spread over all 32 banks (bank = j mod 32, j random).
// ---------------------------------------------------------------------------
__device__ __forceinline__ void bp_deposit(const float* __restrict__ prm,
    int lor, float fk, float* __restrict__ pl)
{
    const float4* p4 = (const float4*)(prm + (size_t)lor * PRM_STRIDE);
    const float4 a = p4[0];
    const float4 b = p4[1];
    const float t = fmaf(fk, b.y, b.x);
    const float u = fmaf(fk, a.y, a.x);
    const float v = fmaf(fk, a.w, a.z);
    const float fi = rintf(u);
    const float fj = rintf(v);
    const int i0 = (int)fi;
    const int j0 = (int)fj;
    const bool tin = (t >= 0.0f) && (t <= 1.0f);
    const float cfs = tin ? b.z : 0.0f;

    const float mi = fi - u;
    const float mj = fj - v;
    const float mim = mi - 1.0f, mip = mi + 1.0f;
    const float mjm = mj - 1.0f, mjp = mj + 1.0f;
    const float exm = __expf(-C2 * mim * mim) * cfs;
    const float ex0 = __expf(-C2 * mi  * mi ) * cfs;
    const float exq = __expf(-C2 * mip * mip) * cfs;
    const float eym = __expf(-C2 * mjm * mjm);
    const float ey0 = __expf(-C2 * mj  * mj );
    const float eyq = __expf(-C2 * mjp * mjp);

    const int ib = min(max(i0 - 1, 0), NG - 3);
    const int jb = min(max(j0 - 1, 0), NG - 3);
    float* base = pl + ib * NG + jb;

    const float exv[3] = {exm, ex0, exq};
#pragma unroll
    for (int aa = 0; aa < 3; ++aa) {
        float* row = base + aa * NG;
        lds_fadd(row + 0, exv[aa] * eym);
        lds_fadd(row + 1, exv[aa] * ey0);
        lds_fadd(row + 2, exv[aa] * eyq);
    }
}

// ---------------------------------------------------------------------------
// All backprojection in one launch. blockIdx.y==0: z+y -> bpsubA (z-family);
// ==1: x -> bpsubB (y-family). NSUB=2 sub-volumes.
// ---------------------------------------------------------------------------
__global__ __launch_bounds__(1024)
void bp_all(const float* __restrict__ prmz, const float* __restrict__ prmy,
            const float* __restrict__ prmx,
            float* __restrict__ bpsubA, float* __restrict__ bpsubB)
{
    __shared__ float pl[NG * NG];              /* 64 KB f32 plane accumulator */
    const int k   = blockIdx.x >> 1;
    const int sub = blockIdx.x & 1;
    const int tid = threadIdx.x;

    for (int i = tid; i < NG * NG; i += 1024) pl[i] = 0.0f;
    __syncthreads();

    const float fk = (float)k;
    const int lo = sub * (NLOR / NSUB), hi = lo + NLOR / NSUB;
    float* bpsub;
    if (blockIdx.y == 0) {
        for (int lor = lo + tid; lor < hi; lor += 1024)
            bp_deposit(prmz, lor, fk, pl);
        for (int lor = lo + tid; lor < hi; lor += 1024)
            bp_deposit(prmy, lor, fk, pl);
        bpsub = bpsubA;
    } else {
        for (int lor = lo + tid; lor < hi; lor += 1024)
            bp_deposit(prmx, lor, fk, pl);
        bpsub = bpsubB;
    }
    __syncthreads();

    float4* out4 = (float4*)(bpsub + ((size_t)sub * NG + k) * PLANE);
    const float4* pl4 = (const float4*)pl;
    for (int i = tid; i < (NG * NG) / 4; i += 1024) out4[i] = pl4[i];
}

extern "C" void kernel_launch(void* const* d_in, const int* in_sizes, int n_in,
                              void* d_out, int out_size, void* d_ws, size_t ws_size,
                              hipStream_t stream) {
    const float* image = (const float*)d_in[0];
    const float* eff   = (const float*)d_in[1];
    const float* xl    = (const float*)d_in[2];
    const float* yl    = (const float*)d_in[3];
    const float* zl    = (const float*)d_in[4];
    float* out = (float*)d_out;

    char* ws = (char*)d_ws;
    __half* imgPz = (__half*)(ws);                       //  4 MB [z][x][y] half
    __half* imgPx = (__half*)(ws + (size_t)( 4 << 20));  //  4 MB [y][z][x] half
    float* bpsubA = (float*)(ws + (size_t)( 8 << 20));   // 16 MB [sub][z][x][y]
    float* bpsubB = (float*)(ws + (size_t)(24 << 20));   // 16 MB [sub][y][z][x]
    float* p8z    = (float*)(ws + (size_t)(40 << 20));   //  4 MB
    float* p8y    = (float*)(ws + (size_t)(44 << 20));   //  4 MB
    float* p8x    = (float*)(ws + (size_t)(48 << 20));   //  4 MB
    float* prmz   = (float*)(ws + (size_t)(52 << 20));   //  2 MB per-LOR params
    float* prmy   = (float*)(ws + (size_t)(54 << 20));   //  2 MB
    float* prmx   = (float*)(ws + (size_t)(56 << 20));   //  2 MB

    const dim3 tb(32, 8);

    // 0) per-LOR affine geometry params (all 3 families)
    lor_prep<<<dim3(NLOR / 256, 3), 256, 0, stream>>>(zl, yl, xl, prmz, prmy, prmx);
    // 1) both image permutes (f32 -> half volumes)
    perm_img2<<<dim3(4, 4, 256), tb, 0, stream>>>(image, imgPz, imgPx);
    // 2) all projections; grid.x = plane group for XCD L2 locality
    proj_all<<<dim3(16, 32, 2), 1024, 0, stream>>>(prmz, prmy, prmx,
        (const unsigned int*)imgPz, (const unsigned int*)imgPx, p8z, p8y, p8x);
    // 3) correction factors -> params slot 6
    reduce_cf3<<<dim3(256, 3), 256, 0, stream>>>(zl, yl, xl, p8z, p8y, p8x, prmz, prmy, prmx);
    // 4) all backprojection (z+y -> bpsubA | x -> bpsubB)
    bp_all<<<dim3(128 * NSUB, 2), 1024, 0, stream>>>(prmz, prmy, prmx, bpsubA, bpsubB);
    // 5) z+y accumulator -> out (overwrite)
    perm_outA<<<dim3(4, 4, 128), tb, 0, stream>>>(bpsubA, out);
    // 6) x accumulator -> out (accumulate + fused finalize)
    perm_outB<<<dim3(4, 4, 128), tb, 0, stream>>>(bpsubB, out, image, eff);
}

// Round 3
// 234.405 us; speedup vs baseline: 5.4953x; 5.4625x over previous
//
#include <hip/hip_runtime.h>
#include <hip/hip_fp16.h>
#include <math.h>

#define NLOR  65536
#define NG    128
#define PLANE (NG * NG)
#define NSUB  2
#define KG    8               /* planes per proj block */
#define NKG   (NG / KG)       /* 16 plane groups */

#define VOX    1.671875f                 /* 214/128 exact */
#define XMIN  (-107.0f)
/* weight arg in cell units: (pi/2)(m+d)^2 */
#define C2     1.57079632679f

#define FPSCALE    8388608.0f            /* 2^23 fixed-point scale */
#define INVFPSCALE (1.0f / 8388608.0f)

// Per-LOR precomputed affine params, 8 floats:
//   [0]=u0 [1]=du [2]=v0 [3]=dv   (y-family stored pre-swapped)
//   [4]=t0 [5]=dt [6]=cf (filled by reduce_cf3) [7]=pad
#define PRM_STRIDE 8

// ---------------------------------------------------------------------------
// Tiled 3D permute body (f32 out). Output ((P*128 + Q)*128 + R); input addr
// P*SP + Q*SQ + R*SR (+ s*volume for NSUM sub-buffers). CONTIG: which of
// {P(0),Q(1)} is the tiled (input-contiguous) axis; the other is b.
// ---------------------------------------------------------------------------
template<int SP, int SQ, int SR, int CONTIG, int NSUM, bool ACCUM, bool FINAL>
__device__ __forceinline__ void permute_body(
    const float* __restrict__ in, float* __restrict__ out,
    const float* __restrict__ img, const float* __restrict__ eff,
    int b, float (*tile)[33])
{
    const int c0 = blockIdx.x * 32;
    const int r0 = blockIdx.y * 32;
    const int tx = threadIdx.x, ty = threadIdx.y;

#pragma unroll
    for (int m = 0; m < 4; ++m) {
        const int C = c0 + tx;
        const int R = r0 + ty + 8 * m;
        const int P = (CONTIG == 0) ? C : b;
        const int Q = (CONTIG == 0) ? b : C;
        const int a = P * SP + Q * SQ + R * SR;
        float v = 0.0f;
#pragma unroll
        for (int s = 0; s < NSUM; ++s) v += in[a + s * NG * PLANE];
        tile[ty + 8 * m][tx] = v;
    }
    __syncthreads();
#pragma unroll
    for (int m = 0; m < 4; ++m) {
        const int R = r0 + tx;
        const int C = c0 + ty + 8 * m;
        const int P = (CONTIG == 0) ? C : b;
        const int Q = (CONTIG == 0) ? b : C;
        const int o = P * PLANE + Q * NG + R;
        float v = tile[tx][ty + 8 * m];
        if (ACCUM) v += out[o];
        if (FINAL) v = img[o] / (eff[o] + 1e-8f) * v;
        out[o] = v;
    }
}

// Same body but writing __half (for the staged image volumes).
template<int SP, int SQ, int SR, int CONTIG>
__device__ __forceinline__ void permute_half_body(
    const float* __restrict__ in, __half* __restrict__ out,
    int b, float (*tile)[33])
{
    const int c0 = blockIdx.x * 32;
    const int r0 = blockIdx.y * 32;
    const int tx = threadIdx.x, ty = threadIdx.y;

#pragma unroll
    for (int m = 0; m < 4; ++m) {
        const int C = c0 + tx;
        const int R = r0 + ty + 8 * m;
        const int P = (CONTIG == 0) ? C : b;
        const int Q = (CONTIG == 0) ? b : C;
        tile[ty + 8 * m][tx] = in[P * SP + Q * SQ + R * SR];
    }
    __syncthreads();
#pragma unroll
    for (int m = 0; m < 4; ++m) {
        const int R = r0 + tx;
        const int C = c0 + ty + 8 * m;
        const int P = (CONTIG == 0) ? C : b;
        const int Q = (CONTIG == 0) ? b : C;
        const int o = P * PLANE + Q * NG + R;
        out[o] = __float2half(tile[tx][ty + 8 * m]);
    }
}

// Both image permutes in one launch: b<128 -> imgPz [z][x][y]; else imgPx [y][z][x].
__global__ __launch_bounds__(256)
void perm_img2(const float* __restrict__ image,
               __half* __restrict__ imgPz, __half* __restrict__ imgPx)
{
    __shared__ float tile[32][33];
    const int b = blockIdx.z;
    if (b < 128)
        permute_half_body<1, 16384, 128, 0>(image, imgPz, b, tile);
    else
        permute_half_body<128, 1, 16384, 1>(image, imgPx, b - 128, tile);
}

__global__ __launch_bounds__(256)
void perm_outA(const float* __restrict__ in, float* __restrict__ out)
{
    __shared__ float tile[32][33];
    permute_body<128, 1, 16384, 1, NSUB, false, false>(in, out, nullptr, nullptr, blockIdx.z, tile);
}

__global__ __launch_bounds__(256)
void perm_outB(const float* __restrict__ in, float* __restrict__ out,
               const float* __restrict__ img, const float* __restrict__ eff)
{
    __shared__ float tile[32][33];
    permute_body<1, 16384, 128, 0, NSUB, true, true>(in, out, img, eff, blockIdx.z, tile);
}

// ---------------------------------------------------------------------------
// Per-LOR affine geometry precompute (runs once, before projection).
// t(k) = t0 + k*dt ; u(k) = u0 + k*du ; v(k) = v0 + k*dv, k = plane index.
// y-family (f==1) stores u/v pre-swapped so downstream kernels are uniform.
// ---------------------------------------------------------------------------
__global__ __launch_bounds__(256)
void lor_prep(const float* __restrict__ zl, const float* __restrict__ yl,
              const float* __restrict__ xl,
              float* __restrict__ prmz, float* __restrict__ prmy,
              float* __restrict__ prmx)
{
    const int f = blockIdx.y;
    const float* lors = (f == 0) ? zl : (f == 1) ? yl : xl;
    float* prm        = (f == 0) ? prmz : (f == 1) ? prmy : prmx;
    const int lor = blockIdx.x * 256 + threadIdx.x;

    const float p1x = lors[0 * NLOR + lor];
    const float p1y = lors[1 * NLOR + lor];
    const float p1z = lors[2 * NLOR + lor];
    const float dx  = lors[3 * NLOR + lor] - p1x;
    const float dy  = lors[4 * NLOR + lor] - p1y;
    float dz = lors[5 * NLOR + lor] - p1z;
    dz = (fabsf(dz) < 1e-6f) ? 1e-6f : dz;
    const float rdz = 1.0f / dz;

    const float t0 = (XMIN + 0.5f * VOX - p1z) * rdz;   /* t at plane k=0 */
    const float dt = VOX * rdz;
    float u0 = (fmaf(t0, dx, p1x) - XMIN) * (1.0f / VOX) - 0.5f;
    float v0 = (fmaf(t0, dy, p1y) - XMIN) * (1.0f / VOX) - 0.5f;
    float du = dx * rdz;
    float dv = dy * rdz;
    if (f == 1) {   /* y-family consumes the z-permuted volume with axes swapped */
        float tmp = u0; u0 = v0; v0 = tmp;
        tmp = du; du = dv; dv = tmp;
    }
    float4* p4 = (float4*)(prm + (size_t)lor * PRM_STRIDE);
    p4[0] = make_float4(u0, du, v0, dv);
    p4[1] = make_float4(t0, dt, 0.0f, 0.0f);
}

// ---------------------------------------------------------------------------
// Projection. Plane staged in LDS as half2 pairs (32 KB). blockIdx.x = plane
// group (XCD = linear_id % 8 = g % 8 -> all chunks of one group share an XCD
// L2, so each XCD fetches only its own groups' planes). blockIdx.y = chunk.
// ---------------------------------------------------------------------------
template<int NS>
__device__ __forceinline__ void proj_body(
    const float* const* prmv, const unsigned int* __restrict__ imgP,
    float* const* p8v, unsigned int* pl)
{
    const int g     = blockIdx.x;          // 16 plane groups (XCD selector)
    const int chunk = blockIdx.y;          // 32 chunks x 2048 LORs
    const int tid   = threadIdx.x;
    const int lor0  = chunk * 2048 + tid;
    const float k0  = (float)(g * KG);

    float tA[2 * NS], uA[2 * NS], vA[2 * NS], dtA[2 * NS], duA[2 * NS], dvA[2 * NS], sA[2 * NS];
#pragma unroll
    for (int s = 0; s < 2 * NS; ++s) {
        const float* prm = prmv[s >> 1];
        const int lor = lor0 + (s & 1) * 1024;
        const float4* p4 = (const float4*)(prm + (size_t)lor * PRM_STRIDE);
        const float4 a = p4[0];
        const float4 b = p4[1];
        tA[s] = fmaf(k0, b.y, b.x);  dtA[s] = b.y;
        uA[s] = fmaf(k0, a.y, a.x);  duA[s] = a.y;
        vA[s] = fmaf(k0, a.w, a.z);  dvA[s] = a.w;
        sA[s] = 0.0f;
    }

    for (int st = 0; st < KG; ++st) {
        const int k = g * KG + st;
        const uint4* src = (const uint4*)(imgP + k * (NG * 64));
        uint4* dst = (uint4*)pl;
        for (int i = tid; i < (NG * 64) / 4; i += 1024) dst[i] = src[i];
        __syncthreads();

        const float fst = (float)st;
#pragma unroll
        for (int s = 0; s < 2 * NS; ++s) {
            const float t = fmaf(fst, dtA[s], tA[s]);
            const float u = fmaf(fst, duA[s], uA[s]);
            const float v = fmaf(fst, dvA[s], vA[s]);
            const int i0 = (int)rintf(u);
            const int j0 = (int)rintf(v);
            const float mi = (float)i0 - u;
            const float mj = (float)j0 - v;
            const float mim = mi - 1.0f, mip = mi + 1.0f;
            const float mjm = mj - 1.0f, mjp = mj + 1.0f;
            const float exm = __expf(-C2 * mim * mim);
            const float ex0 = __expf(-C2 * mi  * mi );
            const float exq = __expf(-C2 * mip * mip);
            const float eym = __expf(-C2 * mjm * mjm);
            const float ey0 = __expf(-C2 * mj  * mj );
            const float eyq = __expf(-C2 * mjp * mjp);

            const int odd = j0 & 1;
            const float lA = odd ? eym : 0.0f;
            const float hA = odd ? ey0 : eym;
            const float lB = odd ? eyq : ey0;
            const float hB = odd ? 0.0f : eyq;
            const int p0 = min(max((j0 - 1) >> 1, 0), 62);
            const int ib = min(max(i0 - 1, 0), 125);

            const float exv[3] = {exm, ex0, exq};
            float acc = 0.0f;
#pragma unroll
            for (int a = 0; a < 3; ++a) {
                const int rowb = (ib + a) << 6;
                const unsigned int Aw = pl[rowb + p0];
                const unsigned int Bw = pl[rowb + p0 + 1];
                const float2 A = __half22float2(*reinterpret_cast<const __half2*>(&Aw));
                const float2 B = __half22float2(*reinterpret_cast<const __half2*>(&Bw));
                acc += exv[a] * (lA * A.x + hA * A.y + lB * B.x + hB * B.y);
            }
            const bool tin = (t >= 0.0f) && (t <= 1.0f);
            sA[s] += tin ? acc : 0.0f;
        }
        __syncthreads();
    }
#pragma unroll
    for (int s = 0; s < NS; ++s) {
        p8v[s][g * NLOR + lor0]        = sA[2 * s];
        p8v[s][g * NLOR + lor0 + 1024] = sA[2 * s + 1];
    }
}

// blockIdx.z==0: z+y streams on imgPz; ==1: x stream on imgPx.
__global__ __launch_bounds__(1024, 8)
void proj_all(const float* __restrict__ prmz, const float* __restrict__ prmy,
              const float* __restrict__ prmx,
              const unsigned int* __restrict__ imgPz, const unsigned int* __restrict__ imgPx,
              float* __restrict__ p8z, float* __restrict__ p8y,
              float* __restrict__ p8x)
{
    __shared__ unsigned int pl[NG * 64];     /* 32 KB: plane as half2 pairs */
    if (blockIdx.z == 0) {
        const float* prmv[2] = {prmz, prmy};
        float* p8v[2] = {p8z, p8y};
        proj_body<2>(prmv, imgPz, p8v, pl);
    } else {
        const float* prmv[1] = {prmx};
        float* p8v[1] = {p8x};
        proj_body<1>(prmv, imgPx, p8v, pl);
    }
}

// ---------------------------------------------------------------------------
// cf for all three passes in one dispatch (blockIdx.y selects the pass).
// Writes cf into slot 6 of the per-LOR param struct (same 32B line bp reads).
// ---------------------------------------------------------------------------
__global__ __launch_bounds__(256)
void reduce_cf3(const float* __restrict__ zl, const float* __restrict__ yl,
                const float* __restrict__ xl,
                const float* __restrict__ p8z, const float* __restrict__ p8y,
                const float* __restrict__ p8x,
                float* __restrict__ prmz, float* __restrict__ prmy,
                float* __restrict__ prmx)
{
    const int which = blockIdx.y;
    const float* lors  = (which == 0) ? zl  : (which == 1) ? yl  : xl;
    const float* part8 = (which == 0) ? p8z : (which == 1) ? p8y : p8x;
    float*       prm   = (which == 0) ? prmz : (which == 1) ? prmy : prmx;

    const int lor = blockIdx.x * 256 + threadIdx.x;
    float s = 0.0f;
#pragma unroll
    for (int g = 0; g < NKG; ++g) s += part8[g * NLOR + lor];

    const float p1x = lors[0 * NLOR + lor];
    const float p1y = lors[1 * NLOR + lor];
    const float p1z = lors[2 * NLOR + lor];
    const float dx  = lors[3 * NLOR + lor] - p1x;
    const float dy  = lors[4 * NLOR + lor] - p1y;
    const float dz0 = lors[5 * NLOR + lor] - p1z;
    const float L = sqrtf(dx * dx + dy * dy + dz0 * dz0);
    const float adz = fmaxf(fabsf(dz0), 1e-6f);
    const float dl = VOX * L / adz;
    prm[(size_t)lor * PRM_STRIDE + 6] = dl / (s * dl + 1e-8f);
}

// ---------------------------------------------------------------------------
// bp deposit: affine params + 9 native u32 fixed-point LDS atomics
// (ds_add_u32). fp32 LDS atomics measured ~10x slower on gfx950 (r1/r2
// post-mortem: 200 cy/wave-op); integer is the fast path. Flat u32 plane:
// bank = j mod 32 (random) -> avg 2-way (free), vs round-0 u64 packing's
// 16 even bank-pairs at 4-way. Headroom: 2^32/2^23 = 512 per voxel/block,
// same as round-0's packed fields (which passed).
// ---------------------------------------------------------------------------
__device__ __forceinline__ void bp_deposit(const float* __restrict__ prm,
    int lor, float fk, unsigned int* __restrict__ pl)
{
    const float4* p4 = (const float4*)(prm + (size_t)lor * PRM_STRIDE);
    const float4 a = p4[0];
    const float4 b = p4[1];
    const float t = fmaf(fk, b.y, b.x);
    const float u = fmaf(fk, a.y, a.x);
    const float v = fmaf(fk, a.w, a.z);
    const bool tin = (t >= 0.0f) && (t <= 1.0f);
    if (!tin) return;

    const float fi = rintf(u);
    const float fj = rintf(v);
    const int i0 = (int)fi;
    const int j0 = (int)fj;
    const float cfs = b.z * FPSCALE;

    const float mi = fi - u;
    const float mj = fj - v;
    const float mim = mi - 1.0f, mip = mi + 1.0f;
    const float mjm = mj - 1.0f, mjp = mj + 1.0f;
    const float exm = __expf(-C2 * mim * mim) * cfs;
    const float ex0 = __expf(-C2 * mi  * mi ) * cfs;
    const float exq = __expf(-C2 * mip * mip) * cfs;
    const float eym = __expf(-C2 * mjm * mjm);
    const float ey0 = __expf(-C2 * mj  * mj );
    const float eyq = __expf(-C2 * mjp * mjp);

    const int ib = min(max(i0 - 1, 0), NG - 3);
    const int jb = min(max(j0 - 1, 0), NG - 3);
    unsigned int* base = pl + ib * NG + jb;

    const float exv[3] = {exm, ex0, exq};
#pragma unroll
    for (int aa = 0; aa < 3; ++aa) {
        unsigned int* row = base + aa * NG;
        atomicAdd(row + 0, (unsigned int)(exv[aa] * eym));
        atomicAdd(row + 1, (unsigned int)(exv[aa] * ey0));
        atomicAdd(row + 2, (unsigned int)(exv[aa] * eyq));
    }
}

// ---------------------------------------------------------------------------
// All backprojection in one launch. blockIdx.y==0: z+y -> bpsubA (z-family);
// ==1: x -> bpsubB (y-family). NSUB=2 sub-volumes.
// ---------------------------------------------------------------------------
__global__ __launch_bounds__(1024)
void bp_all(const float* __restrict__ prmz, const float* __restrict__ prmy,
            const float* __restrict__ prmx,
            float* __restrict__ bpsubA, float* __restrict__ bpsubB)
{
    __shared__ unsigned int pl[NG * NG];       /* 32 KB u32 fixed-point plane */
    const int k   = blockIdx.x >> 1;
    const int sub = blockIdx.x & 1;
    const int tid = threadIdx.x;

    for (int i = tid; i < NG * NG; i += 1024) pl[i] = 0u;
    __syncthreads();

    const float fk = (float)k;
    const int lo = sub * (NLOR / NSUB), hi = lo + NLOR / NSUB;
    float* bpsub;
    if (blockIdx.y == 0) {
        for (int lor = lo + tid; lor < hi; lor += 1024)
            bp_deposit(prmz, lor, fk, pl);
        for (int lor = lo + tid; lor < hi; lor += 1024)
            bp_deposit(prmy, lor, fk, pl);
        bpsub = bpsubA;
    } else {
        for (int lor = lo + tid; lor < hi; lor += 1024)
            bp_deposit(prmx, lor, fk, pl);
        bpsub = bpsubB;
    }
    __syncthreads();

    float4* out4 = (float4*)(bpsub + ((size_t)sub * NG + k) * PLANE);
    const uint4* pl4 = (const uint4*)pl;
    for (int i = tid; i < (NG * NG) / 4; i += 1024) {
        const uint4 vv = pl4[i];
        out4[i] = make_float4((float)vv.x * INVFPSCALE, (float)vv.y * INVFPSCALE,
                              (float)vv.z * INVFPSCALE, (float)vv.w * INVFPSCALE);
    }
}

extern "C" void kernel_launch(void* const* d_in, const int* in_sizes, int n_in,
                              void* d_out, int out_size, void* d_ws, size_t ws_size,
                              hipStream_t stream) {
    const float* image = (const float*)d_in[0];
    const float* eff   = (const float*)d_in[1];
    const float* xl    = (const float*)d_in[2];
    const float* yl    = (const float*)d_in[3];
    const float* zl    = (const float*)d_in[4];
    float* out = (float*)d_out;

    char* ws = (char*)d_ws;
    __half* imgPz = (__half*)(ws);                       //  4 MB [z][x][y] half
    __half* imgPx = (__half*)(ws + (size_t)( 4 << 20));  //  4 MB [y][z][x] half
    float* bpsubA = (float*)(ws + (size_t)( 8 << 20));   // 16 MB [sub][z][x][y]
    float* bpsubB = (float*)(ws + (size_t)(24 << 20));   // 16 MB [sub][y][z][x]
    float* p8z    = (float*)(ws + (size_t)(40 << 20));   //  4 MB
    float* p8y    = (float*)(ws + (size_t)(44 << 20));   //  4 MB
    float* p8x    = (float*)(ws + (size_t)(48 << 20));   //  4 MB
    float* prmz   = (float*)(ws + (size_t)(52 << 20));   //  2 MB per-LOR params
    float* prmy   = (float*)(ws + (size_t)(54 << 20));   //  2 MB
    float* prmx   = (float*)(ws + (size_t)(56 << 20));   //  2 MB

    const dim3 tb(32, 8);

    // 0) per-LOR affine geometry params (all 3 families)
    lor_prep<<<dim3(NLOR / 256, 3), 256, 0, stream>>>(zl, yl, xl, prmz, prmy, prmx);
    // 1) both image permutes (f32 -> half volumes)
    perm_img2<<<dim3(4, 4, 256), tb, 0, stream>>>(image, imgPz, imgPx);
    // 2) all projections; grid.x = plane group for XCD L2 locality
    proj_all<<<dim3(16, 32, 2), 1024, 0, stream>>>(prmz, prmy, prmx,
        (const unsigned int*)imgPz, (const unsigned int*)imgPx, p8z, p8y, p8x);
    // 3) correction factors -> params slot 6
    reduce_cf3<<<dim3(256, 3), 256, 0, stream>>>(zl, yl, xl, p8z, p8y, p8x, prmz, prmy, prmx);
    // 4) all backprojection (z+y -> bpsubA | x -> bpsubB)
    bp_all<<<dim3(128 * NSUB, 2), 1024, 0, stream>>>(prmz, prmy, prmx, bpsubA, bpsubB);
    // 5) z+y accumulator -> out (overwrite)
    perm_outA<<<dim3(4, 4, 128), tb, 0, stream>>>(bpsubA, out);
    // 6) x accumulator -> out (accumulate + fused finalize)
    perm_outB<<<dim3(4, 4, 128), tb, 0, stream>>>(bpsubB, out, image, eff);
}

// Round 4
// 226.674 us; speedup vs baseline: 5.6828x; 1.0341x over previous
//
#include <hip/hip_runtime.h>
#include <hip/hip_fp16.h>
#include <math.h>

#define NLOR  65536
#define NG    128
#define PLANE (NG * NG)
#define NSUB  2
#define KG    8               /* planes per proj block */
#define NKG   (NG / KG)       /* 16 plane groups */

#define VOX    1.671875f                 /* 214/128 exact */
#define XMIN  (-107.0f)
/* weight arg in cell units: (pi/2)(m+d)^2 */
#define C2     1.57079632679f

#define FPSCALE    8388608.0f            /* 2^23 fixed-point scale */
#define INVFPSCALE (1.0f / 8388608.0f)

/* padded LDS accumulator stride: bank=(i+j)%32 uniform for atomics, and the
   transposed writeout read (lanes over i, stride 129) is conflict-free */
#define PLP    129

// Per-LOR precomputed affine params, 8 floats:
//   [0]=u0 [1]=du [2]=v0 [3]=dv   (y-family stored pre-swapped)
//   [4]=t0 [5]=dt [6]=cf (filled by reduce_cf3) [7]=pad
#define PRM_STRIDE 8

// ---------------------------------------------------------------------------
// Tiled 3D permute body for the half-precision staged image volumes.
// ---------------------------------------------------------------------------
template<int SP, int SQ, int SR, int CONTIG>
__device__ __forceinline__ void permute_half_body(
    const float* __restrict__ in, __half* __restrict__ out,
    int b, float (*tile)[33])
{
    const int c0 = blockIdx.x * 32;
    const int r0 = blockIdx.y * 32;
    const int tx = threadIdx.x, ty = threadIdx.y;

#pragma unroll
    for (int m = 0; m < 4; ++m) {
        const int C = c0 + tx;
        const int R = r0 + ty + 8 * m;
        const int P = (CONTIG == 0) ? C : b;
        const int Q = (CONTIG == 0) ? b : C;
        tile[ty + 8 * m][tx] = in[P * SP + Q * SQ + R * SR];
    }
    __syncthreads();
#pragma unroll
    for (int m = 0; m < 4; ++m) {
        const int R = r0 + tx;
        const int C = c0 + ty + 8 * m;
        const int P = (CONTIG == 0) ? C : b;
        const int Q = (CONTIG == 0) ? b : C;
        const int o = P * PLANE + Q * NG + R;
        out[o] = __float2half(tile[tx][ty + 8 * m]);
    }
}

// ---------------------------------------------------------------------------
// Fused: both image permutes + per-LOR affine param precompute.
// b<128 -> imgPz [z][x][y]; b<256 -> imgPx [y][z][x]; b>=256 -> lor_prep
// (48 slices x 16 xy-blocks x 256 thr = 196608 = 3 x 65536 LORs).
// ---------------------------------------------------------------------------
__global__ __launch_bounds__(256)
void perm_img2(const float* __restrict__ image,
               __half* __restrict__ imgPz, __half* __restrict__ imgPx,
               const float* __restrict__ zl, const float* __restrict__ yl,
               const float* __restrict__ xl,
               float* __restrict__ prmz, float* __restrict__ prmy,
               float* __restrict__ prmx)
{
    __shared__ float tile[32][33];
    const int b = blockIdx.z;
    if (b < 128) {
        permute_half_body<1, 16384, 128, 0>(image, imgPz, b, tile);
        return;
    }
    if (b < 256) {
        permute_half_body<128, 1, 16384, 1>(image, imgPx, b - 128, tile);
        return;
    }
    // ---- LOR prep ----
    const int linear = (b - 256) * 16 + blockIdx.y * 4 + blockIdx.x;
    const int gid = linear * 256 + threadIdx.y * 32 + threadIdx.x;
    const int f   = gid >> 16;              /* family: uniform per block */
    const int lor = gid & (NLOR - 1);
    const float* lors = (f == 0) ? zl : (f == 1) ? yl : xl;
    float* prm        = (f == 0) ? prmz : (f == 1) ? prmy : prmx;

    const float p1x = lors[0 * NLOR + lor];
    const float p1y = lors[1 * NLOR + lor];
    const float p1z = lors[2 * NLOR + lor];
    const float dx  = lors[3 * NLOR + lor] - p1x;
    const float dy  = lors[4 * NLOR + lor] - p1y;
    float dz = lors[5 * NLOR + lor] - p1z;
    dz = (fabsf(dz) < 1e-6f) ? 1e-6f : dz;
    const float rdz = 1.0f / dz;

    const float t0 = (XMIN + 0.5f * VOX - p1z) * rdz;   /* t at plane k=0 */
    const float dt = VOX * rdz;
    float u0 = (fmaf(t0, dx, p1x) - XMIN) * (1.0f / VOX) - 0.5f;
    float v0 = (fmaf(t0, dy, p1y) - XMIN) * (1.0f / VOX) - 0.5f;
    float du = dx * rdz;
    float dv = dy * rdz;
    if (f == 1) {   /* y-family consumes the z-permuted volume with axes swapped */
        float tmp = u0; u0 = v0; v0 = tmp;
        tmp = du; du = dv; dv = tmp;
    }
    float4* p4 = (float4*)(prm + (size_t)lor * PRM_STRIDE);
    p4[0] = make_float4(u0, du, v0, dv);
    p4[1] = make_float4(t0, dt, 0.0f, 0.0f);
}

// ---------------------------------------------------------------------------
// Projection. Plane staged in LDS as half2 pairs (32 KB). blockIdx.x = plane
// group (XCD = linear_id % 8 = g % 8 -> all chunks of one group share an XCD
// L2, so each XCD fetches only its own groups' planes). blockIdx.y = chunk.
// ---------------------------------------------------------------------------
template<int NS>
__device__ __forceinline__ void proj_body(
    const float* const* prmv, const unsigned int* __restrict__ imgP,
    float* const* p8v, unsigned int* pl)
{
    const int g     = blockIdx.x;          // 16 plane groups (XCD selector)
    const int chunk = blockIdx.y;          // 32 chunks x 2048 LORs
    const int tid   = threadIdx.x;
    const int lor0  = chunk * 2048 + tid;
    const float k0  = (float)(g * KG);

    float tA[2 * NS], uA[2 * NS], vA[2 * NS], dtA[2 * NS], duA[2 * NS], dvA[2 * NS], sA[2 * NS];
#pragma unroll
    for (int s = 0; s < 2 * NS; ++s) {
        const float* prm = prmv[s >> 1];
        const int lor = lor0 + (s & 1) * 1024;
        const float4* p4 = (const float4*)(prm + (size_t)lor * PRM_STRIDE);
        const float4 a = p4[0];
        const float4 b = p4[1];
        tA[s] = fmaf(k0, b.y, b.x);  dtA[s] = b.y;
        uA[s] = fmaf(k0, a.y, a.x);  duA[s] = a.y;
        vA[s] = fmaf(k0, a.w, a.z);  dvA[s] = a.w;
        sA[s] = 0.0f;
    }

    for (int st = 0; st < KG; ++st) {
        const int k = g * KG + st;
        const uint4* src = (const uint4*)(imgP + k * (NG * 64));
        uint4* dst = (uint4*)pl;
        for (int i = tid; i < (NG * 64) / 4; i += 1024) dst[i] = src[i];
        __syncthreads();

        const float fst = (float)st;
#pragma unroll
        for (int s = 0; s < 2 * NS; ++s) {
            const float t = fmaf(fst, dtA[s], tA[s]);
            const float u = fmaf(fst, duA[s], uA[s]);
            const float v = fmaf(fst, dvA[s], vA[s]);
            const int i0 = (int)rintf(u);
            const int j0 = (int)rintf(v);
            const float mi = (float)i0 - u;
            const float mj = (float)j0 - v;
            const float mim = mi - 1.0f, mip = mi + 1.0f;
            const float mjm = mj - 1.0f, mjp = mj + 1.0f;
            const float exm = __expf(-C2 * mim * mim);
            const float ex0 = __expf(-C2 * mi  * mi );
            const float exq = __expf(-C2 * mip * mip);
            const float eym = __expf(-C2 * mjm * mjm);
            const float ey0 = __expf(-C2 * mj  * mj );
            const float eyq = __expf(-C2 * mjp * mjp);

            const int odd = j0 & 1;
            const float lA = odd ? eym : 0.0f;
            const float hA = odd ? ey0 : eym;
            const float lB = odd ? eyq : ey0;
            const float hB = odd ? 0.0f : eyq;
            const int p0 = min(max((j0 - 1) >> 1, 0), 62);
            const int ib = min(max(i0 - 1, 0), 125);

            const float exv[3] = {exm, ex0, exq};
            float acc = 0.0f;
#pragma unroll
            for (int a = 0; a < 3; ++a) {
                const int rowb = (ib + a) << 6;
                const unsigned int Aw = pl[rowb + p0];
                const unsigned int Bw = pl[rowb + p0 + 1];
                const float2 A = __half22float2(*reinterpret_cast<const __half2*>(&Aw));
                const float2 B = __half22float2(*reinterpret_cast<const __half2*>(&Bw));
                acc += exv[a] * (lA * A.x + hA * A.y + lB * B.x + hB * B.y);
            }
            const bool tin = (t >= 0.0f) && (t <= 1.0f);
            sA[s] += tin ? acc : 0.0f;
        }
        __syncthreads();
    }
#pragma unroll
    for (int s = 0; s < NS; ++s) {
        p8v[s][g * NLOR + lor0]        = sA[2 * s];
        p8v[s][g * NLOR + lor0 + 1024] = sA[2 * s + 1];
    }
}

// blockIdx.z==0: z+y streams on imgPz; ==1: x stream on imgPx.
__global__ __launch_bounds__(1024, 8)
void proj_all(const float* __restrict__ prmz, const float* __restrict__ prmy,
              const float* __restrict__ prmx,
              const unsigned int* __restrict__ imgPz, const unsigned int* __restrict__ imgPx,
              float* __restrict__ p8z, float* __restrict__ p8y,
              float* __restrict__ p8x)
{
    __shared__ unsigned int pl[NG * 64];     /* 32 KB: plane as half2 pairs */
    if (blockIdx.z == 0) {
        const float* prmv[2] = {prmz, prmy};
        float* p8v[2] = {p8z, p8y};
        proj_body<2>(prmv, imgPz, p8v, pl);
    } else {
        const float* prmv[1] = {prmx};
        float* p8v[1] = {p8x};
        proj_body<1>(prmv, imgPx, p8v, pl);
    }
}

// ---------------------------------------------------------------------------
// cf for all three passes in one dispatch (blockIdx.y selects the pass).
// Writes cf into slot 6 of the per-LOR param struct (same 32B line bp reads).
// ---------------------------------------------------------------------------
__global__ __launch_bounds__(256)
void reduce_cf3(const float* __restrict__ zl, const float* __restrict__ yl,
                const float* __restrict__ xl,
                const float* __restrict__ p8z, const float* __restrict__ p8y,
                const float* __restrict__ p8x,
                float* __restrict__ prmz, float* __restrict__ prmy,
                float* __restrict__ prmx)
{
    const int which = blockIdx.y;
    const float* lors  = (which == 0) ? zl  : (which == 1) ? yl  : xl;
    const float* part8 = (which == 0) ? p8z : (which == 1) ? p8y : p8x;
    float*       prm   = (which == 0) ? prmz : (which == 1) ? prmy : prmx;

    const int lor = blockIdx.x * 256 + threadIdx.x;
    float s = 0.0f;
#pragma unroll
    for (int g = 0; g < NKG; ++g) s += part8[g * NLOR + lor];

    const float p1x = lors[0 * NLOR + lor];
    const float p1y = lors[1 * NLOR + lor];
    const float p1z = lors[2 * NLOR + lor];
    const float dx  = lors[3 * NLOR + lor] - p1x;
    const float dy  = lors[4 * NLOR + lor] - p1y;
    const float dz0 = lors[5 * NLOR + lor] - p1z;
    const float L = sqrtf(dx * dx + dy * dy + dz0 * dz0);
    const float adz = fmaxf(fabsf(dz0), 1e-6f);
    const float dl = VOX * L / adz;
    prm[(size_t)lor * PRM_STRIDE + 6] = dl / (s * dl + 1e-8f);
}

// ---------------------------------------------------------------------------
// bp deposit: affine params + 9 native u32 fixed-point LDS atomics
// (ds_add_u32; fp32 LDS atomics measured ~10x slower on gfx950, r1/r2).
// Padded accumulator stride PLP=129: bank=(i+j)%32 stays uniform.
// ---------------------------------------------------------------------------
__device__ __forceinline__ void bp_deposit(const float* __restrict__ prm,
    int lor, float fk, unsigned int* __restrict__ pl)
{
    const float4* p4 = (const float4*)(prm + (size_t)lor * PRM_STRIDE);
    const float4 a = p4[0];
    const float4 b = p4[1];
    const float t = fmaf(fk, b.y, b.x);
    const float u = fmaf(fk, a.y, a.x);
    const float v = fmaf(fk, a.w, a.z);
    const bool tin = (t >= 0.0f) && (t <= 1.0f);
    if (!tin) return;

    const float fi = rintf(u);
    const float fj = rintf(v);
    const int i0 = (int)fi;
    const int j0 = (int)fj;
    const float cfs = b.z * FPSCALE;

    const float mi = fi - u;
    const float mj = fj - v;
    const float mim = mi - 1.0f, mip = mi + 1.0f;
    const float mjm = mj - 1.0f, mjp = mj + 1.0f;
    const float exm = __expf(-C2 * mim * mim) * cfs;
    const float ex0 = __expf(-C2 * mi  * mi ) * cfs;
    const float exq = __expf(-C2 * mip * mip) * cfs;
    const float eym = __expf(-C2 * mjm * mjm);
    const float ey0 = __expf(-C2 * mj  * mj );
    const float eyq = __expf(-C2 * mjp * mjp);

    const int ib = min(max(i0 - 1, 0), NG - 3);
    const int jb = min(max(j0 - 1, 0), NG - 3);
    unsigned int* base = pl + ib * PLP + jb;

    const float exv[3] = {exm, ex0, exq};
#pragma unroll
    for (int aa = 0; aa < 3; ++aa) {
        unsigned int* row = base + aa * PLP;
        atomicAdd(row + 0, (unsigned int)(exv[aa] * eym));
        atomicAdd(row + 1, (unsigned int)(exv[aa] * ey0));
        atomicAdd(row + 2, (unsigned int)(exv[aa] * eyq));
    }
}

// ---------------------------------------------------------------------------
// All backprojection in one launch. blockIdx.y==0: z+y -> bpA; ==1: x -> bpB.
// Writes planes TRANSPOSED: bpA = A'[s][z][y][x], bpB = B'[s][y][x][z]
// (padded-LDS transposed read is conflict-free; enables single-pass finalize).
// z- and y-family deposits interleaved in one loop + unroll: 4 independent
// dependency chains per iteration to lift VALUBusy past 63%.
// ---------------------------------------------------------------------------
__global__ __launch_bounds__(1024)
void bp_all(const float* __restrict__ prmz, const float* __restrict__ prmy,
            const float* __restrict__ prmx,
            float* __restrict__ bpA, float* __restrict__ bpB)
{
    __shared__ unsigned int pl[NG * PLP];      /* 64.5 KB padded u32 plane */
    const int k   = blockIdx.x >> 1;
    const int sub = blockIdx.x & 1;
    const int tid = threadIdx.x;

    for (int i = tid; i < NG * PLP; i += 1024) pl[i] = 0u;
    __syncthreads();

    const float fk = (float)k;
    const int lo = sub * (NLOR / NSUB);
    constexpr int NIT = (NLOR / NSUB) / 1024;   /* 32 */
    float* bpsub;
    if (blockIdx.y == 0) {
#pragma unroll 2
        for (int it = 0; it < NIT; ++it) {
            const int lor = lo + tid + it * 1024;
            bp_deposit(prmz, lor, fk, pl);
            bp_deposit(prmy, lor, fk, pl);
        }
        bpsub = bpA;
    } else {
#pragma unroll 4
        for (int it = 0; it < NIT; ++it)
            bp_deposit(prmx, lo + tid + it * 1024, fk, pl);
        bpsub = bpB;
    }
    __syncthreads();

    /* transposed writeout: dst[q*128 + p] = pl[p][q]; LDS lanes stride PLP
       (conflict-free), global contiguous */
    float* dst = bpsub + ((size_t)(sub * NG + k)) * PLANE;
    for (int idx = tid; idx < PLANE; idx += 1024)
        dst[idx] = (float)pl[(idx & 127) * PLP + (idx >> 7)] * INVFPSCALE;
}

// ---------------------------------------------------------------------------
// Single-pass finalize: out[x][y][z] = img/eff * (sum_s A'[s][z][y][x]
//                                              +  sum_s B'[s][y][x][z]).
// Block = 32x x 32z tile at fixed y=b. A side needs one LDS transpose
// (load lanes over x, emit lanes over z); B side + img/eff/out are already
// contiguous in z.
// ---------------------------------------------------------------------------
__global__ __launch_bounds__(256)
void finalize_out(const float* __restrict__ bpA, const float* __restrict__ bpB,
                  const float* __restrict__ img, const float* __restrict__ eff,
                  float* __restrict__ out)
{
    __shared__ float tA[32][33];
    const int b  = blockIdx.z;              /* y */
    const int x0 = blockIdx.x * 32;
    const int z0 = blockIdx.y * 32;
    const int tx = threadIdx.x, ty = threadIdx.y;
    const int VOL = NG * PLANE;

#pragma unroll
    for (int m = 0; m < 4; ++m) {
        const int z = z0 + ty + 8 * m;
        const int a = z * PLANE + b * NG + (x0 + tx);
        tA[ty + 8 * m][tx] = bpA[a] + bpA[a + VOL];
    }
    __syncthreads();
#pragma unroll
    for (int m = 0; m < 4; ++m) {
        const int x  = x0 + ty + 8 * m;
        const int o  = x * PLANE + b * NG + (z0 + tx);
        const int bb = b * PLANE + x * NG + (z0 + tx);
        const float v = tA[tx][ty + 8 * m] + bpB[bb] + bpB[bb + VOL];
        out[o] = img[o] / (eff[o] + 1e-8f) * v;
    }
}

extern "C" void kernel_launch(void* const* d_in, const int* in_sizes, int n_in,
                              void* d_out, int out_size, void* d_ws, size_t ws_size,
                              hipStream_t stream) {
    const float* image = (const float*)d_in[0];
    const float* eff   = (const float*)d_in[1];
    const float* xl    = (const float*)d_in[2];
    const float* yl    = (const float*)d_in[3];
    const float* zl    = (const float*)d_in[4];
    float* out = (float*)d_out;

    char* ws = (char*)d_ws;
    __half* imgPz = (__half*)(ws);                       //  4 MB [z][x][y] half
    __half* imgPx = (__half*)(ws + (size_t)( 4 << 20));  //  4 MB [y][z][x] half
    float* bpA    = (float*)(ws + (size_t)( 8 << 20));   // 16 MB A'[s][z][y][x]
    float* bpB    = (float*)(ws + (size_t)(24 << 20));   // 16 MB B'[s][y][x][z]
    float* p8z    = (float*)(ws + (size_t)(40 << 20));   //  4 MB
    float* p8y    = (float*)(ws + (size_t)(44 << 20));   //  4 MB
    float* p8x    = (float*)(ws + (size_t)(48 << 20));   //  4 MB
    float* prmz   = (float*)(ws + (size_t)(52 << 20));   //  2 MB per-LOR params
    float* prmy   = (float*)(ws + (size_t)(54 << 20));   //  2 MB
    float* prmx   = (float*)(ws + (size_t)(56 << 20));   //  2 MB

    const dim3 tb(32, 8);

    // 1) image permutes + LOR param prep, one launch (z slices 256..303 = prep)
    perm_img2<<<dim3(4, 4, 304), tb, 0, stream>>>(image, imgPz, imgPx,
        zl, yl, xl, prmz, prmy, prmx);
    // 2) all projections; grid.x = plane group for XCD L2 locality
    proj_all<<<dim3(16, 32, 2), 1024, 0, stream>>>(prmz, prmy, prmx,
        (const unsigned int*)imgPz, (const unsigned int*)imgPx, p8z, p8y, p8x);
    // 3) correction factors -> params slot 6
    reduce_cf3<<<dim3(256, 3), 256, 0, stream>>>(zl, yl, xl, p8z, p8y, p8x, prmz, prmy, prmx);
    // 4) all backprojection (z+y -> bpA | x -> bpB), transposed plane writeout
    bp_all<<<dim3(128 * NSUB, 2), 1024, 0, stream>>>(prmz, prmy, prmx, bpA, bpB);
    // 5) fused gather + finalize (single pass over out)
    finalize_out<<<dim3(4, 4, 128), tb, 0, stream>>>(bpA, bpB, image, eff, out);
}

// Round 5
// 206.842 us; speedup vs baseline: 6.2276x; 1.0959x over previous
//
#include <hip/hip_runtime.h>
#include <hip/hip_fp16.h>
#include <math.h>

#define NLOR  65536
#define NG    128
#define PLANE (NG * NG)
#define NSUB  2
#define KG    8               /* planes per proj block */
#define NKG   (NG / KG)       /* 16 plane groups */

#define VOX    1.671875f                 /* 214/128 exact */
#define XMIN  (-107.0f)
/* weight arg in cell units: (pi/2)(m+d)^2 ; C2L = (pi/2)*log2(e) */
#define C2     1.57079632679f
#define C2L    2.26618007f

#define FPSCALE    8388608.0f            /* 2^23 fixed-point scale */
#define INVFPSCALE (1.0f / 8388608.0f)

/* padded LDS accumulator stride */
#define PLP    129

// Per-LOR precomputed affine params, 8 floats:
//   [0]=u0 [1]=du [2]=v0 [3]=dv   (y-family stored pre-swapped)
//   [4]=t0 [5]=dt [6]=cf*2^23 (filled by reduce_cf3) [7]=pad
#define PRM_STRIDE 8

// ---------------------------------------------------------------------------
// Tiled 3D permute body for the half-precision staged image volumes.
// ---------------------------------------------------------------------------
template<int SP, int SQ, int SR, int CONTIG>
__device__ __forceinline__ void permute_half_body(
    const float* __restrict__ in, __half* __restrict__ out,
    int b, float (*tile)[33])
{
    const int c0 = blockIdx.x * 32;
    const int r0 = blockIdx.y * 32;
    const int tx = threadIdx.x, ty = threadIdx.y;

#pragma unroll
    for (int m = 0; m < 4; ++m) {
        const int C = c0 + tx;
        const int R = r0 + ty + 8 * m;
        const int P = (CONTIG == 0) ? C : b;
        const int Q = (CONTIG == 0) ? b : C;
        tile[ty + 8 * m][tx] = in[P * SP + Q * SQ + R * SR];
    }
    __syncthreads();
#pragma unroll
    for (int m = 0; m < 4; ++m) {
        const int R = r0 + tx;
        const int C = c0 + ty + 8 * m;
        const int P = (CONTIG == 0) ? C : b;
        const int Q = (CONTIG == 0) ? b : C;
        const int o = P * PLANE + Q * NG + R;
        out[o] = __float2half(tile[tx][ty + 8 * m]);
    }
}

// ---------------------------------------------------------------------------
// Fused: both image permutes + per-LOR affine param precompute.
// b<128 -> imgPz [z][x][y]; b<256 -> imgPx [y][z][x]; b>=256 -> lor_prep
// (48 slices x 16 xy-blocks x 256 thr = 196608 = 3 x 65536 LORs).
// ---------------------------------------------------------------------------
__global__ __launch_bounds__(256)
void perm_img2(const float* __restrict__ image,
               __half* __restrict__ imgPz, __half* __restrict__ imgPx,
               const float* __restrict__ zl, const float* __restrict__ yl,
               const float* __restrict__ xl,
               float* __restrict__ prmz, float* __restrict__ prmy,
               float* __restrict__ prmx)
{
    __shared__ float tile[32][33];
    const int b = blockIdx.z;
    if (b < 128) {
        permute_half_body<1, 16384, 128, 0>(image, imgPz, b, tile);
        return;
    }
    if (b < 256) {
        permute_half_body<128, 1, 16384, 1>(image, imgPx, b - 128, tile);
        return;
    }
    // ---- LOR prep ----
    const int linear = (b - 256) * 16 + blockIdx.y * 4 + blockIdx.x;
    const int gid = linear * 256 + threadIdx.y * 32 + threadIdx.x;
    const int f   = gid >> 16;              /* family: uniform per block */
    const int lor = gid & (NLOR - 1);
    const float* lors = (f == 0) ? zl : (f == 1) ? yl : xl;
    float* prm        = (f == 0) ? prmz : (f == 1) ? prmy : prmx;

    const float p1x = lors[0 * NLOR + lor];
    const float p1y = lors[1 * NLOR + lor];
    const float p1z = lors[2 * NLOR + lor];
    const float dx  = lors[3 * NLOR + lor] - p1x;
    const float dy  = lors[4 * NLOR + lor] - p1y;
    float dz = lors[5 * NLOR + lor] - p1z;
    dz = (fabsf(dz) < 1e-6f) ? 1e-6f : dz;
    const float rdz = 1.0f / dz;

    const float t0 = (XMIN + 0.5f * VOX - p1z) * rdz;   /* t at plane k=0 */
    const float dt = VOX * rdz;
    float u0 = (fmaf(t0, dx, p1x) - XMIN) * (1.0f / VOX) - 0.5f;
    float v0 = (fmaf(t0, dy, p1y) - XMIN) * (1.0f / VOX) - 0.5f;
    float du = dx * rdz;
    float dv = dy * rdz;
    if (f == 1) {   /* y-family consumes the z-permuted volume with axes swapped */
        float tmp = u0; u0 = v0; v0 = tmp;
        tmp = du; du = dv; dv = tmp;
    }
    float4* p4 = (float4*)(prm + (size_t)lor * PRM_STRIDE);
    p4[0] = make_float4(u0, du, v0, dv);
    p4[1] = make_float4(t0, dt, 0.0f, 0.0f);
}

// ---------------------------------------------------------------------------
// Projection. Plane staged in LDS as half2 pairs (32 KB). blockIdx.x = plane
// group (XCD selector). blockIdx.y = chunk. Weights via exp2-domain
// recurrence: 3 v_exp + ~6 VALU per dim (saves the per-weight arg muls).
// ---------------------------------------------------------------------------
template<int NS>
__device__ __forceinline__ void proj_body(
    const float* const* prmv, const unsigned int* __restrict__ imgP,
    float* const* p8v, unsigned int* pl)
{
    const int g     = blockIdx.x;          // 16 plane groups (XCD selector)
    const int chunk = blockIdx.y;          // 32 chunks x 2048 LORs
    const int tid   = threadIdx.x;
    const int lor0  = chunk * 2048 + tid;
    const float k0  = (float)(g * KG);

    float tA[2 * NS], uA[2 * NS], vA[2 * NS], dtA[2 * NS], duA[2 * NS], dvA[2 * NS], sA[2 * NS];
#pragma unroll
    for (int s = 0; s < 2 * NS; ++s) {
        const float* prm = prmv[s >> 1];
        const int lor = lor0 + (s & 1) * 1024;
        const float4* p4 = (const float4*)(prm + (size_t)lor * PRM_STRIDE);
        const float4 a = p4[0];
        const float4 b = p4[1];
        tA[s] = fmaf(k0, b.y, b.x);  dtA[s] = b.y;
        uA[s] = fmaf(k0, a.y, a.x);  duA[s] = a.y;
        vA[s] = fmaf(k0, a.w, a.z);  dvA[s] = a.w;
        sA[s] = 0.0f;
    }

    for (int st = 0; st < KG; ++st) {
        const int k = g * KG + st;
        const uint4* src = (const uint4*)(imgP + k * (NG * 64));
        uint4* dst = (uint4*)pl;
        for (int i = tid; i < (NG * 64) / 4; i += 1024) dst[i] = src[i];
        __syncthreads();

        const float fst = (float)st;
#pragma unroll
        for (int s = 0; s < 2 * NS; ++s) {
            const float t = fmaf(fst, dtA[s], tA[s]);
            const float u = fmaf(fst, duA[s], uA[s]);
            const float v = fmaf(fst, dvA[s], vA[s]);
            const float fi = rintf(u);
            const float fj = rintf(v);
            const int i0 = (int)fi;
            const int j0 = (int)fj;
            const float mi = fi - u;
            const float mj = fj - v;
            const float ci = -C2L * mi,  cj = -C2L * mj;
            const float a0i = ci * mi,   a0j = cj * mj;
            const float gi = ci + ci,    gj = cj + cj;
            const float ki = a0i - C2L,  kj = a0j - C2L;
            const float exm = __builtin_amdgcn_exp2f(ki - gi);
            const float ex0 = __builtin_amdgcn_exp2f(a0i);
            const float exq = __builtin_amdgcn_exp2f(ki + gi);
            const float eym = __builtin_amdgcn_exp2f(kj - gj);
            const float ey0 = __builtin_amdgcn_exp2f(a0j);
            const float eyq = __builtin_amdgcn_exp2f(kj + gj);

            const int odd = j0 & 1;
            const float lA = odd ? eym : 0.0f;
            const float hA = odd ? ey0 : eym;
            const float lB = odd ? eyq : ey0;
            const float hB = odd ? 0.0f : eyq;
            const int p0 = min(max((j0 - 1) >> 1, 0), 62);
            const int ib = min(max(i0 - 1, 0), 125);

            const float exv[3] = {exm, ex0, exq};
            float acc = 0.0f;
#pragma unroll
            for (int a = 0; a < 3; ++a) {
                const int rowb = (ib + a) << 6;
                const unsigned int Aw = pl[rowb + p0];
                const unsigned int Bw = pl[rowb + p0 + 1];
                const float2 A = __half22float2(*reinterpret_cast<const __half2*>(&Aw));
                const float2 B = __half22float2(*reinterpret_cast<const __half2*>(&Bw));
                acc += exv[a] * (lA * A.x + hA * A.y + lB * B.x + hB * B.y);
            }
            const bool tin = (t >= 0.0f) && (t <= 1.0f);
            sA[s] += tin ? acc : 0.0f;
        }
        __syncthreads();
    }
#pragma unroll
    for (int s = 0; s < NS; ++s) {
        p8v[s][g * NLOR + lor0]        = sA[2 * s];
        p8v[s][g * NLOR + lor0 + 1024] = sA[2 * s + 1];
    }
}

// blockIdx.z==0: z+y streams on imgPz; ==1: x stream on imgPx.
__global__ __launch_bounds__(1024, 8)
void proj_all(const float* __restrict__ prmz, const float* __restrict__ prmy,
              const float* __restrict__ prmx,
              const unsigned int* __restrict__ imgPz, const unsigned int* __restrict__ imgPx,
              float* __restrict__ p8z, float* __restrict__ p8y,
              float* __restrict__ p8x)
{
    __shared__ unsigned int pl[NG * 64];     /* 32 KB: plane as half2 pairs */
    if (blockIdx.z == 0) {
        const float* prmv[2] = {prmz, prmy};
        float* p8v[2] = {p8z, p8y};
        proj_body<2>(prmv, imgPz, p8v, pl);
    } else {
        const float* prmv[1] = {prmx};
        float* p8v[1] = {p8x};
        proj_body<1>(prmv, imgPx, p8v, pl);
    }
}

// ---------------------------------------------------------------------------
// cf for all three passes in one dispatch (blockIdx.y selects the pass).
// Stores cf PRE-SCALED by 2^23 into slot 6 (saves a mul per bp deposit).
// ---------------------------------------------------------------------------
__global__ __launch_bounds__(256)
void reduce_cf3(const float* __restrict__ zl, const float* __restrict__ yl,
                const float* __restrict__ xl,
                const float* __restrict__ p8z, const float* __restrict__ p8y,
                const float* __restrict__ p8x,
                float* __restrict__ prmz, float* __restrict__ prmy,
                float* __restrict__ prmx)
{
    const int which = blockIdx.y;
    const float* lors  = (which == 0) ? zl  : (which == 1) ? yl  : xl;
    const float* part8 = (which == 0) ? p8z : (which == 1) ? p8y : p8x;
    float*       prm   = (which == 0) ? prmz : (which == 1) ? prmy : prmx;

    const int lor = blockIdx.x * 256 + threadIdx.x;
    float s = 0.0f;
#pragma unroll
    for (int g = 0; g < NKG; ++g) s += part8[g * NLOR + lor];

    const float p1x = lors[0 * NLOR + lor];
    const float p1y = lors[1 * NLOR + lor];
    const float p1z = lors[2 * NLOR + lor];
    const float dx  = lors[3 * NLOR + lor] - p1x;
    const float dy  = lors[4 * NLOR + lor] - p1y;
    const float dz0 = lors[5 * NLOR + lor] - p1z;
    const float L = sqrtf(dx * dx + dy * dy + dz0 * dz0);
    const float adz = fmaxf(fabsf(dz0), 1e-6f);
    const float dl = VOX * L / adz;
    prm[(size_t)lor * PRM_STRIDE + 6] = (dl / (s * dl + 1e-8f)) * FPSCALE;
}

// ---------------------------------------------------------------------------
// bp deposit, op-minimized (round-4 post-mortem: bp is at its VALU floor,
// so cut the op count): exp2-domain weight recurrence (6 v_exp + 12 VALU
// for all six weights), float-domain med3 clamp + single fma address
// (9 ds immediate offsets off one base), select instead of branch,
// pre-scaled cf. u32 fixed-point LDS atomics (fp32 LDS atomics are ~10x
// slower on gfx950, r1/r2).
// ---------------------------------------------------------------------------
__device__ __forceinline__ void bp_deposit(const float* __restrict__ prm,
    int lor, float fk, unsigned int* __restrict__ pl)
{
    const float4* p4 = (const float4*)(prm + (size_t)lor * PRM_STRIDE);
    const float4 a = p4[0];
    const float4 b = p4[1];
    const float t = fmaf(fk, b.y, b.x);
    const float u = fmaf(fk, a.y, a.x);
    const float v = fmaf(fk, a.w, a.z);
    const float fi = rintf(u);
    const float fj = rintf(v);
    const float cfs = ((t >= 0.0f) && (t <= 1.0f)) ? b.z : 0.0f;  /* cf*2^23 */

    const float mi = fi - u;
    const float mj = fj - v;
    const float ci = -C2L * mi,  cj = -C2L * mj;
    const float a0i = ci * mi,   a0j = cj * mj;
    const float gi = ci + ci,    gj = cj + cj;
    const float ki = a0i - C2L,  kj = a0j - C2L;

    const float ex0 = __builtin_amdgcn_exp2f(a0i) * cfs;
    const float exm = __builtin_amdgcn_exp2f(ki - gi) * cfs;
    const float exq = __builtin_amdgcn_exp2f(ki + gi) * cfs;
    const float ey0 = __builtin_amdgcn_exp2f(a0j);
    const float eym = __builtin_amdgcn_exp2f(kj - gj);
    const float eyq = __builtin_amdgcn_exp2f(kj + gj);

    /* clamp in float, one fma -> flat index; 9 targets = imm ds offsets */
    const float fib = __builtin_amdgcn_fmed3f(fi, 1.0f, 126.0f);
    const float fjb = __builtin_amdgcn_fmed3f(fj, 1.0f, 126.0f);
    const int idx = (int)fmaf(fib, (float)PLP, fjb) - (PLP + 1);
    unsigned int* base = pl + idx;

    const float exv[3] = {exm, ex0, exq};
#pragma unroll
    for (int aa = 0; aa < 3; ++aa) {
        unsigned int* row = base + aa * PLP;
        atomicAdd(row + 0, (unsigned int)(exv[aa] * eym));
        atomicAdd(row + 1, (unsigned int)(exv[aa] * ey0));
        atomicAdd(row + 2, (unsigned int)(exv[aa] * eyq));
    }
}

// ---------------------------------------------------------------------------
// All backprojection in one launch. blockIdx.y==0: z+y -> bpA; ==1: x -> bpB.
// Writes planes TRANSPOSED: bpA = A'[s][z][y][x], bpB = B'[s][y][x][z].
// ---------------------------------------------------------------------------
__global__ __launch_bounds__(1024)
void bp_all(const float* __restrict__ prmz, const float* __restrict__ prmy,
            const float* __restrict__ prmx,
            float* __restrict__ bpA, float* __restrict__ bpB)
{
    __shared__ unsigned int pl[NG * PLP];      /* 64.5 KB padded u32 plane */
    const int k   = blockIdx.x >> 1;
    const int sub = blockIdx.x & 1;
    const int tid = threadIdx.x;

    for (int i = tid; i < NG * PLP; i += 1024) pl[i] = 0u;
    __syncthreads();

    const float fk = (float)k;
    const int lo = sub * (NLOR / NSUB);
    constexpr int NIT = (NLOR / NSUB) / 1024;   /* 32 */
    float* bpsub;
    if (blockIdx.y == 0) {
#pragma unroll 2
        for (int it = 0; it < NIT; ++it) {
            const int lor = lo + tid + it * 1024;
            bp_deposit(prmz, lor, fk, pl);
            bp_deposit(prmy, lor, fk, pl);
        }
        bpsub = bpA;
    } else {
#pragma unroll 4
        for (int it = 0; it < NIT; ++it)
            bp_deposit(prmx, lo + tid + it * 1024, fk, pl);
        bpsub = bpB;
    }
    __syncthreads();

    /* transposed writeout: dst[q*128 + p] = pl[p][q]; LDS lanes stride PLP
       (conflict-free), global contiguous */
    float* dst = bpsub + ((size_t)(sub * NG + k)) * PLANE;
    for (int idx = tid; idx < PLANE; idx += 1024)
        dst[idx] = (float)pl[(idx & 127) * PLP + (idx >> 7)] * INVFPSCALE;
}

// ---------------------------------------------------------------------------
// Single-pass finalize: out[x][y][z] = img/eff * (sum_s A'[s][z][y][x]
//                                              +  sum_s B'[s][y][x][z]).
// ---------------------------------------------------------------------------
__global__ __launch_bounds__(256)
void finalize_out(const float* __restrict__ bpA, const float* __restrict__ bpB,
                  const float* __restrict__ img, const float* __restrict__ eff,
                  float* __restrict__ out)
{
    __shared__ float tA[32][33];
    const int b  = blockIdx.z;              /* y */
    const int x0 = blockIdx.x * 32;
    const int z0 = blockIdx.y * 32;
    const int tx = threadIdx.x, ty = threadIdx.y;
    const int VOL = NG * PLANE;

#pragma unroll
    for (int m = 0; m < 4; ++m) {
        const int z = z0 + ty + 8 * m;
        const int a = z * PLANE + b * NG + (x0 + tx);
        tA[ty + 8 * m][tx] = bpA[a] + bpA[a + VOL];
    }
    __syncthreads();
#pragma unroll
    for (int m = 0; m < 4; ++m) {
        const int x  = x0 + ty + 8 * m;
        const int o  = x * PLANE + b * NG + (z0 + tx);
        const int bb = b * PLANE + x * NG + (z0 + tx);
        const float v = tA[tx][ty + 8 * m] + bpB[bb] + bpB[bb + VOL];
        out[o] = img[o] / (eff[o] + 1e-8f) * v;
    }
}

extern "C" void kernel_launch(void* const* d_in, const int* in_sizes, int n_in,
                              void* d_out, int out_size, void* d_ws, size_t ws_size,
                              hipStream_t stream) {
    const float* image = (const float*)d_in[0];
    const float* eff   = (const float*)d_in[1];
    const float* xl    = (const float*)d_in[2];
    const float* yl    = (const float*)d_in[3];
    const float* zl    = (const float*)d_in[4];
    float* out = (float*)d_out;

    char* ws = (char*)d_ws;
    __half* imgPz = (__half*)(ws);                       //  4 MB [z][x][y] half
    __half* imgPx = (__half*)(ws + (size_t)( 4 << 20));  //  4 MB [y][z][x] half
    float* bpA    = (float*)(ws + (size_t)( 8 << 20));   // 16 MB A'[s][z][y][x]
    float* bpB    = (float*)(ws + (size_t)(24 << 20));   // 16 MB B'[s][y][x][z]
    float* p8z    = (float*)(ws + (size_t)(40 << 20));   //  4 MB
    float* p8y    = (float*)(ws + (size_t)(44 << 20));   //  4 MB
    float* p8x    = (float*)(ws + (size_t)(48 << 20));   //  4 MB
    float* prmz   = (float*)(ws + (size_t)(52 << 20));   //  2 MB per-LOR params
    float* prmy   = (float*)(ws + (size_t)(54 << 20));   //  2 MB
    float* prmx   = (float*)(ws + (size_t)(56 << 20));   //  2 MB

    const dim3 tb(32, 8);

    // 1) image permutes + LOR param prep, one launch (z slices 256..303 = prep)
    perm_img2<<<dim3(4, 4, 304), tb, 0, stream>>>(image, imgPz, imgPx,
        zl, yl, xl, prmz, prmy, prmx);
    // 2) all projections; grid.x = plane group for XCD L2 locality
    proj_all<<<dim3(16, 32, 2), 1024, 0, stream>>>(prmz, prmy, prmx,
        (const unsigned int*)imgPz, (const unsigned int*)imgPx, p8z, p8y, p8x);
    // 3) correction factors (pre-scaled by 2^23) -> params slot 6
    reduce_cf3<<<dim3(256, 3), 256, 0, stream>>>(zl, yl, xl, p8z, p8y, p8x, prmz, prmy, prmx);
    // 4) all backprojection (z+y -> bpA | x -> bpB), transposed plane writeout
    bp_all<<<dim3(128 * NSUB, 2), 1024, 0, stream>>>(prmz, prmy, prmx, bpA, bpB);
    // 5) fused gather + finalize (single pass over out)
    finalize_out<<<dim3(4, 4, 128), tb, 0, stream>>>(bpA, bpB, image, eff, out);
}